// Round 3
// baseline (8048.876 us; speedup 1.0000x reference)
//
#include <hip/hip_runtime.h>
#include <math.h>

#define NN   50000
#define NE   800000
#define DIM  128
#define KMSG 259      // 2*DIM + 3
#define KUPD 256      // 2*DIM
#define STEPS 4
#define LN_EPS 1e-5f

#define EPB 64        // edges per block (NE % EPB == 0)
#define NPB 64        // nodes per block

// ---------------- receiver counts -> 1/max(count,1) ----------------
__global__ void count_kernel(const int* __restrict__ ei, float* __restrict__ cnt) {
    int e = blockIdx.x * 256 + threadIdx.x;
    if (e < NE) atomicAdd(&cnt[ei[NE + e]], 1.0f);
}

__global__ void dinv_kernel(float* __restrict__ cnt) {
    int n = blockIdx.x * 256 + threadIdx.x;
    if (n < NN) cnt[n] = 1.0f / fmaxf(cnt[n], 1.0f);
}

// ---------------- message: GEMM + GELU + LN + scatter-add ----------------
// block = 256 threads: dg = tid&31 owns dims [4dg,4dg+3], eg = tid>>5 owns edges [8eg,8eg+7]
__global__ __launch_bounds__(256, 2)
void msg_kernel(const float* __restrict__ h, const float* __restrict__ pos,
                const int* __restrict__ ei,
                const float* __restrict__ W, const float* __restrict__ bias,
                const float* __restrict__ gam, const float* __restrict__ bet,
                float* __restrict__ agg) {
    __shared__ float in0[EPB][KMSG + 1];   // 64 x 260 f32
    __shared__ int rowS[EPB], colS[EPB];

    const int tid = threadIdx.x;
    const int ebase = blockIdx.x * EPB;

    if (tid < EPB) {
        int e = ebase + tid;
        int r = ei[e];
        int c = ei[NE + e];
        rowS[tid] = r; colS[tid] = c;
        in0[tid][256] = pos[r*3+0] - pos[c*3+0];
        in0[tid][257] = pos[r*3+1] - pos[c*3+1];
        in0[tid][258] = pos[r*3+2] - pos[c*3+2];
    }
    __syncthreads();
    for (int i = tid; i < EPB * DIM; i += 256) {
        int e = i >> 7, d = i & 127;
        in0[e][d]       = h[(size_t)rowS[e] * DIM + d];
        in0[e][DIM + d] = h[(size_t)colS[e] * DIM + d];
    }
    __syncthreads();

    const int dg = tid & 31;
    const int eg = tid >> 5;
    const float4* W4 = (const float4*)W;

    float4 bv = ((const float4*)bias)[dg];
    float acc[8][4];
    #pragma unroll
    for (int e = 0; e < 8; ++e) {
        acc[e][0] = bv.x; acc[e][1] = bv.y; acc[e][2] = bv.z; acc[e][3] = bv.w;
    }

    const float* inb = &in0[eg * 8][0];
    for (int k = 0; k < KMSG; ++k) {
        float4 w = W4[k * 32 + dg];
        #pragma unroll
        for (int e = 0; e < 8; ++e) {
            float a = inb[e * (KMSG + 1) + k];
            acc[e][0] = fmaf(a, w.x, acc[e][0]);
            acc[e][1] = fmaf(a, w.y, acc[e][1]);
            acc[e][2] = fmaf(a, w.z, acc[e][2]);
            acc[e][3] = fmaf(a, w.w, acc[e][3]);
        }
    }

    // exact GELU
    #pragma unroll
    for (int e = 0; e < 8; ++e)
        #pragma unroll
        for (int j = 0; j < 4; ++j) {
            float x = acc[e][j];
            acc[e][j] = 0.5f * x * (1.0f + erff(x * 0.70710678118654752f));
        }

    float4 gv  = ((const float4*)gam)[dg];
    float4 bev = ((const float4*)bet)[dg];
    float gj[4] = {gv.x, gv.y, gv.z, gv.w};
    float bj[4] = {bev.x, bev.y, bev.z, bev.w};

    #pragma unroll
    for (int e = 0; e < 8; ++e) {
        float s = acc[e][0] + acc[e][1] + acc[e][2] + acc[e][3];
        float q = acc[e][0]*acc[e][0] + acc[e][1]*acc[e][1]
                + acc[e][2]*acc[e][2] + acc[e][3]*acc[e][3];
        #pragma unroll
        for (int off = 16; off > 0; off >>= 1) {
            s += __shfl_xor(s, off, 32);
            q += __shfl_xor(q, off, 32);
        }
        float mu  = s * (1.0f / 128.0f);
        float var = q * (1.0f / 128.0f) - mu * mu;
        float rs  = rsqrtf(var + LN_EPS);
        int c = colS[eg * 8 + e];
        float* ap = &agg[(size_t)c * DIM + dg * 4];
        #pragma unroll
        for (int j = 0; j < 4; ++j) {
            float m = (acc[e][j] - mu) * rs * gj[j] + bj[j];
            atomicAdd(&ap[j], m);
        }
    }
}

// ---------------- update: GEMM + LN + residual ----------------
__global__ __launch_bounds__(256, 2)
void upd_kernel(float* __restrict__ h, const float* __restrict__ agg,
                const float* __restrict__ dinv,
                const float* __restrict__ W, const float* __restrict__ bias,
                const float* __restrict__ gam, const float* __restrict__ bet) {
    __shared__ float uin[NPB][KUPD];   // 64 x 256 f32

    const int tid = threadIdx.x;
    const int nbase = blockIdx.x * NPB;

    for (int i = tid; i < NPB * DIM; i += 256) {
        int n = i >> 7, d = i & 127;
        int node = nbase + n;
        if (node < NN) {
            uin[n][d]       = h[(size_t)node * DIM + d];
            uin[n][DIM + d] = agg[(size_t)node * DIM + d] * dinv[node];
        } else {
            uin[n][d] = 0.0f; uin[n][DIM + d] = 0.0f;
        }
    }
    __syncthreads();

    const int dg = tid & 31;
    const int ng = tid >> 5;
    const float4* W4 = (const float4*)W;

    float4 bv = ((const float4*)bias)[dg];
    float acc[8][4];
    #pragma unroll
    for (int n = 0; n < 8; ++n) {
        acc[n][0] = bv.x; acc[n][1] = bv.y; acc[n][2] = bv.z; acc[n][3] = bv.w;
    }

    const float* inb = &uin[ng * 8][0];
    for (int k = 0; k < KUPD; ++k) {
        float4 w = W4[k * 32 + dg];
        #pragma unroll
        for (int n = 0; n < 8; ++n) {
            float a = inb[n * KUPD + k];
            acc[n][0] = fmaf(a, w.x, acc[n][0]);
            acc[n][1] = fmaf(a, w.y, acc[n][1]);
            acc[n][2] = fmaf(a, w.z, acc[n][2]);
            acc[n][3] = fmaf(a, w.w, acc[n][3]);
        }
    }

    float4 gv  = ((const float4*)gam)[dg];
    float4 bev = ((const float4*)bet)[dg];
    float gj[4] = {gv.x, gv.y, gv.z, gv.w};
    float bj[4] = {bev.x, bev.y, bev.z, bev.w};

    #pragma unroll
    for (int n = 0; n < 8; ++n) {
        float s = acc[n][0] + acc[n][1] + acc[n][2] + acc[n][3];
        float q = acc[n][0]*acc[n][0] + acc[n][1]*acc[n][1]
                + acc[n][2]*acc[n][2] + acc[n][3]*acc[n][3];
        #pragma unroll
        for (int off = 16; off > 0; off >>= 1) {
            s += __shfl_xor(s, off, 32);
            q += __shfl_xor(q, off, 32);
        }
        float mu  = s * (1.0f / 128.0f);
        float var = q * (1.0f / 128.0f) - mu * mu;
        float rs  = rsqrtf(var + LN_EPS);
        int node = nbase + ng * 8 + n;
        if (node < NN) {
            #pragma unroll
            for (int j = 0; j < 4; ++j) {
                float u = (acc[n][j] - mu) * rs * gj[j] + bj[j];
                h[(size_t)node * DIM + dg * 4 + j] = uin[ng * 8 + n][dg * 4 + j] + u;
            }
        }
    }
}

// ---------------- driver ----------------
extern "C" void kernel_launch(void* const* d_in, const int* in_sizes, int n_in,
                              void* d_out, int out_size, void* d_ws, size_t ws_size,
                              hipStream_t stream) {
    const float* x      = (const float*)d_in[0];
    const float* pos    = (const float*)d_in[1];
    const int*   ei     = (const int*)d_in[2];   // int64 in ref, delivered as int32
    const float* msg_W  = (const float*)d_in[3];
    const float* msg_b  = (const float*)d_in[4];
    const float* msg_g  = (const float*)d_in[5];
    const float* msg_be = (const float*)d_in[6];
    const float* upd_W  = (const float*)d_in[7];
    const float* upd_b  = (const float*)d_in[8];
    const float* upd_g  = (const float*)d_in[9];
    const float* upd_be = (const float*)d_in[10];

    float* h = (float*)d_out;                       // h lives in d_out
    char*  ws = (char*)d_ws;
    float* agg  = (float*)ws;                       // NN*DIM f32
    float* dinv = (float*)(ws + (size_t)NN * DIM * sizeof(float)); // NN f32

    // h = x
    hipMemcpyAsync(h, x, (size_t)NN * DIM * sizeof(float),
                   hipMemcpyDeviceToDevice, stream);

    // counts -> 1/max(cnt,1)
    hipMemsetAsync(dinv, 0, (size_t)NN * sizeof(float), stream);
    count_kernel<<<(NE + 255) / 256, 256, 0, stream>>>(ei, dinv);
    dinv_kernel<<<(NN + 255) / 256, 256, 0, stream>>>(dinv);

    for (int s = 0; s < STEPS; ++s) {
        hipMemsetAsync(agg, 0, (size_t)NN * DIM * sizeof(float), stream);
        msg_kernel<<<NE / EPB, 256, 0, stream>>>(
            h, pos, ei,
            msg_W + (size_t)s * KMSG * DIM, msg_b + (size_t)s * DIM,
            msg_g + (size_t)s * DIM, msg_be + (size_t)s * DIM, agg);
        upd_kernel<<<(NN + NPB - 1) / NPB, 256, 0, stream>>>(
            h, agg, dinv,
            upd_W + (size_t)s * KUPD * DIM, upd_b + (size_t)s * DIM,
            upd_g + (size_t)s * DIM, upd_be + (size_t)s * DIM);
    }
}

// Round 4
// 2251.037 us; speedup vs baseline: 3.5756x; 3.5756x over previous
//
#include <hip/hip_runtime.h>
#include <math.h>

#define NN   50000
#define NE   800000
#define DIM  128
#define KMSG 259      // 2*DIM + 3
#define KUPD 256      // 2*DIM
#define STEPS 4
#define LN_EPS 1e-5f

#define EPB 64        // edges per block (NE % EPB == 0 -> 12500 blocks)
#define NPB 64        // nodes per block
#define KPAD 288      // 9 * 32 (K padded for MFMA)
#define NKS  9        // K slices of 32
#define NNT  8        // N tiles of 16
#define APITCH 296    // KPAD + 8 bf16 pad -> row stride 592B = 37*16B (odd) -> conflict-free b128

typedef __attribute__((ext_vector_type(8))) short bf16x8;
typedef __attribute__((ext_vector_type(4))) float f32x4;
typedef unsigned short u16;

__device__ __forceinline__ u16 f2b(float f) {   // RNE f32 -> bf16
    union { float f; unsigned u; } v; v.f = f;
    unsigned r = (v.u + 0x7fffu + ((v.u >> 16) & 1u)) >> 16;
    return (u16)r;
}

// ---------------- receiver counts -> 1/max(count,1) ----------------
__global__ void count_kernel(const int* __restrict__ ei, float* __restrict__ cnt) {
    int e = blockIdx.x * 256 + threadIdx.x;
    if (e < NE) atomicAdd(&cnt[ei[NE + e]], 1.0f);
}

__global__ void dinv_kernel(float* __restrict__ cnt) {
    int n = blockIdx.x * 256 + threadIdx.x;
    if (n < NN) cnt[n] = 1.0f / fmaxf(cnt[n], 1.0f);
}

// ---------------- h (f32) -> hb (bf16) ----------------
__global__ void h2b_kernel(const float* __restrict__ h, u16* __restrict__ hb) {
    int i = blockIdx.x * 256 + threadIdx.x;
    if (i < NN * DIM / 4) {
        float4 v = ((const float4*)h)[i];
        ushort4 o;
        o.x = f2b(v.x); o.y = f2b(v.y); o.z = f2b(v.z); o.w = f2b(v.w);
        ((ushort4*)hb)[i] = o;
    }
}

// ---------------- msg_W -> B-fragment-ordered bf16 ----------------
// Wf[s][ks][nt][lane][j] = bf16(W[s][ks*32 + (lane>>4)*8 + j][nt*16 + (lane&15)]), 0 if k>=259
__global__ void wmsg_kernel(const float* __restrict__ W, u16* __restrict__ Wf) {
    int i = blockIdx.x * 256 + threadIdx.x;
    if (i >= STEPS * NKS * NNT * 64 * 8) return;
    int j    = i & 7;
    int lane = (i >> 3) & 63;
    int nt   = (i >> 9) & 7;
    int ks   = (i >> 12) % NKS;
    int s    = (i >> 12) / NKS;
    int k = ks * 32 + (lane >> 4) * 8 + j;
    int n = nt * 16 + (lane & 15);
    float w = (k < KMSG) ? W[((size_t)s * KMSG + k) * DIM + n] : 0.0f;
    Wf[i] = f2b(w);
}

// ---------------- message: bf16 MFMA GEMM + GELU + LN + atomic scatter ----------------
__global__ __launch_bounds__(256, 4)
void msg_kernel(const u16* __restrict__ hb, const float* __restrict__ pos,
                const int* __restrict__ ei, const u16* __restrict__ Wf,
                const float* __restrict__ bias, const float* __restrict__ gam,
                const float* __restrict__ bet, float* __restrict__ agg) {
    __shared__ u16 A[EPB][APITCH];
    __shared__ int rowS[EPB], colS[EPB];

    const int tid = threadIdx.x;
    const int ebase = blockIdx.x * EPB;

    if (tid < EPB) {
        int e = ebase + tid;
        int r = ei[e], c = ei[NE + e];
        rowS[tid] = r; colS[tid] = c;
        A[tid][256] = f2b(pos[r * 3 + 0] - pos[c * 3 + 0]);
        A[tid][257] = f2b(pos[r * 3 + 1] - pos[c * 3 + 1]);
        A[tid][258] = f2b(pos[r * 3 + 2] - pos[c * 3 + 2]);
        #pragma unroll
        for (int k = KMSG; k < KPAD; ++k) A[tid][k] = 0;
    }
    __syncthreads();

    // gather h rows as bf16: 64 edges * 2 rows * 128 dims / 8 = 2048 16B chunks
    for (int i = tid; i < 2048; i += 256) {
        int e = i >> 5;
        int c = i & 31;                       // 0-15: row-half, 16-31: col-half
        int node = (c < 16) ? rowS[e] : colS[e];
        int d = (c & 15) * 8;
        bf16x8 v = *(const bf16x8*)(hb + (size_t)node * DIM + d);
        *(bf16x8*)&A[e][((c < 16) ? 0 : DIM) + d] = v;
    }
    __syncthreads();

    const int wave = tid >> 6;
    const int lane = tid & 63;
    const int l15 = lane & 15;
    const int lhi = lane >> 4;                // 0..3

    f32x4 acc[NNT];
    #pragma unroll
    for (int t = 0; t < NNT; ++t) acc[t] = (f32x4){0.f, 0.f, 0.f, 0.f};

    // A-frag: lane -> row m = wave*16 + l15, k = ks*32 + lhi*8 + j  (16B contiguous)
    const u16* Arow = &A[wave * 16 + l15][lhi * 8];

    #pragma unroll
    for (int ks = 0; ks < NKS; ++ks) {
        bf16x8 a = *(const bf16x8*)(Arow + ks * 32);
        const u16* wp = Wf + (size_t)(ks * NNT) * 512 + lane * 8;
        #pragma unroll
        for (int nt = 0; nt < NNT; ++nt) {
            bf16x8 b = *(const bf16x8*)(wp + nt * 512);
            acc[nt] = __builtin_amdgcn_mfma_f32_16x16x32_bf16(a, b, acc[nt], 0, 0, 0);
        }
    }

    // per-lane column params (n = nt*16 + l15)
    float bs[NNT], gs[NNT], be[NNT];
    #pragma unroll
    for (int t = 0; t < NNT; ++t) {
        int n = t * 16 + l15;
        bs[t] = bias[n]; gs[t] = gam[n]; be[t] = bet[n];
    }

    // bias + exact GELU (in place) + LN stats per row r (edge m = lhi*4 + r)
    float s0[4] = {0.f, 0.f, 0.f, 0.f}, q0[4] = {0.f, 0.f, 0.f, 0.f};
    #pragma unroll
    for (int t = 0; t < NNT; ++t)
        #pragma unroll
        for (int r = 0; r < 4; ++r) {
            float x = acc[t][r] + bs[t];
            x = 0.5f * x * (1.0f + erff(x * 0.70710678118654752f));
            acc[t][r] = x;
            s0[r] += x; q0[r] += x * x;
        }
    #pragma unroll
    for (int r = 0; r < 4; ++r)
        #pragma unroll
        for (int off = 1; off < 16; off <<= 1) {
            s0[r] += __shfl_xor(s0[r], off);
            q0[r] += __shfl_xor(q0[r], off);
        }

    #pragma unroll
    for (int r = 0; r < 4; ++r) {
        float mu  = s0[r] * (1.0f / 128.0f);
        float var = q0[r] * (1.0f / 128.0f) - mu * mu;
        float rs  = rsqrtf(var + LN_EPS);
        int cnode = colS[wave * 16 + lhi * 4 + r];
        float* ap = agg + (size_t)cnode * DIM + l15;
        #pragma unroll
        for (int t = 0; t < NNT; ++t) {
            float m = (acc[t][r] - mu) * rs * gs[t] + be[t];
            atomicAdd(ap + t * 16, m);
        }
    }
}

// ---------------- update: f32 GEMM + LN + residual (unchanged) ----------------
__global__ __launch_bounds__(256, 2)
void upd_kernel(float* __restrict__ h, const float* __restrict__ agg,
                const float* __restrict__ dinv,
                const float* __restrict__ W, const float* __restrict__ bias,
                const float* __restrict__ gam, const float* __restrict__ bet) {
    __shared__ float uin[NPB][KUPD];

    const int tid = threadIdx.x;
    const int nbase = blockIdx.x * NPB;

    for (int i = tid; i < NPB * DIM; i += 256) {
        int n = i >> 7, d = i & 127;
        int node = nbase + n;
        if (node < NN) {
            uin[n][d]       = h[(size_t)node * DIM + d];
            uin[n][DIM + d] = agg[(size_t)node * DIM + d] * dinv[node];
        } else {
            uin[n][d] = 0.0f; uin[n][DIM + d] = 0.0f;
        }
    }
    __syncthreads();

    const int dg = tid & 31;
    const int ng = tid >> 5;
    const float4* W4 = (const float4*)W;

    float4 bv = ((const float4*)bias)[dg];
    float acc[8][4];
    #pragma unroll
    for (int n = 0; n < 8; ++n) {
        acc[n][0] = bv.x; acc[n][1] = bv.y; acc[n][2] = bv.z; acc[n][3] = bv.w;
    }

    const float* inb = &uin[ng * 8][0];
    for (int k = 0; k < KUPD; ++k) {
        float4 w = W4[k * 32 + dg];
        #pragma unroll
        for (int n = 0; n < 8; ++n) {
            float a = inb[n * KUPD + k];
            acc[n][0] = fmaf(a, w.x, acc[n][0]);
            acc[n][1] = fmaf(a, w.y, acc[n][1]);
            acc[n][2] = fmaf(a, w.z, acc[n][2]);
            acc[n][3] = fmaf(a, w.w, acc[n][3]);
        }
    }

    float4 gv  = ((const float4*)gam)[dg];
    float4 bev = ((const float4*)bet)[dg];
    float gj[4] = {gv.x, gv.y, gv.z, gv.w};
    float bj[4] = {bev.x, bev.y, bev.z, bev.w};

    #pragma unroll
    for (int n = 0; n < 8; ++n) {
        float s = acc[n][0] + acc[n][1] + acc[n][2] + acc[n][3];
        float q = acc[n][0]*acc[n][0] + acc[n][1]*acc[n][1]
                + acc[n][2]*acc[n][2] + acc[n][3]*acc[n][3];
        #pragma unroll
        for (int off = 16; off > 0; off >>= 1) {
            s += __shfl_xor(s, off, 32);
            q += __shfl_xor(q, off, 32);
        }
        float mu  = s * (1.0f / 128.0f);
        float var = q * (1.0f / 128.0f) - mu * mu;
        float rs  = rsqrtf(var + LN_EPS);
        int node = nbase + ng * 8 + n;
        if (node < NN) {
            #pragma unroll
            for (int j = 0; j < 4; ++j) {
                float u = (acc[n][j] - mu) * rs * gj[j] + bj[j];
                h[(size_t)node * DIM + dg * 4 + j] = uin[ng * 8 + n][dg * 4 + j] + u;
            }
        }
    }
}

// ---------------- driver ----------------
extern "C" void kernel_launch(void* const* d_in, const int* in_sizes, int n_in,
                              void* d_out, int out_size, void* d_ws, size_t ws_size,
                              hipStream_t stream) {
    const float* x      = (const float*)d_in[0];
    const float* pos    = (const float*)d_in[1];
    const int*   ei     = (const int*)d_in[2];   // delivered as int32
    const float* msg_W  = (const float*)d_in[3];
    const float* msg_b  = (const float*)d_in[4];
    const float* msg_g  = (const float*)d_in[5];
    const float* msg_be = (const float*)d_in[6];
    const float* upd_W  = (const float*)d_in[7];
    const float* upd_b  = (const float*)d_in[8];
    const float* upd_g  = (const float*)d_in[9];
    const float* upd_be = (const float*)d_in[10];

    float* h = (float*)d_out;
    char*  ws = (char*)d_ws;
    // ws layout (256B aligned)
    float* agg  = (float*)ws;                               // 25,600,000 B
    float* dinv = (float*)(ws + 25600000);                  //    200,000 B
    u16*   hb   = (u16*)(ws + 25800192);                    // 12,800,000 B
    u16*   Wf   = (u16*)(ws + 38600192);                    //    294,912 B

    hipMemcpyAsync(h, x, (size_t)NN * DIM * sizeof(float),
                   hipMemcpyDeviceToDevice, stream);

    hipMemsetAsync(dinv, 0, (size_t)NN * sizeof(float), stream);
    count_kernel<<<(NE + 255) / 256, 256, 0, stream>>>(ei, dinv);
    dinv_kernel<<<(NN + 255) / 256, 256, 0, stream>>>(dinv);

    // pre-swizzle msg weights for all 4 steps (B-fragment order, K zero-padded)
    wmsg_kernel<<<(STEPS * NKS * NNT * 64 * 8 + 255) / 256, 256, 0, stream>>>(msg_W, Wf);

    for (int s = 0; s < STEPS; ++s) {
        h2b_kernel<<<(NN * DIM / 4 + 255) / 256, 256, 0, stream>>>(h, hb);
        hipMemsetAsync(agg, 0, (size_t)NN * DIM * sizeof(float), stream);
        msg_kernel<<<NE / EPB, 256, 0, stream>>>(
            hb, pos, ei, Wf + (size_t)s * NKS * NNT * 512,
            msg_b + (size_t)s * DIM, msg_g + (size_t)s * DIM,
            msg_be + (size_t)s * DIM, agg);
        upd_kernel<<<(NN + NPB - 1) / NPB, 256, 0, stream>>>(
            h, agg, dinv,
            upd_W + (size_t)s * KUPD * DIM, upd_b + (size_t)s * DIM,
            upd_g + (size_t)s * DIM, upd_be + (size_t)s * DIM);
    }
}

// Round 5
// 1635.022 us; speedup vs baseline: 4.9228x; 1.3768x over previous
//
#include <hip/hip_runtime.h>
#include <math.h>

#define NN   50000
#define NE   800000
#define DIM  128
#define KMSG 259      // 2*DIM + 3
#define KUPD 256      // 2*DIM
#define STEPS 4
#define LN_EPS 1e-5f

#define EPB 64        // edges per block (NE % EPB == 0 -> 12500 blocks)
#define KPAD 288      // 9 * 32 (K padded for MFMA)
#define NKS  9        // msg K slices of 32
#define NKSU 8        // upd K slices of 32
#define NNT  8        // N tiles of 16
#define APITCH 296    // msg A pitch: 592B rows (odd*16B) -> 2-way (free) ds_read_b128
#define UPITCH 264    // upd A pitch: 528B rows -> 2-way (free)

typedef __attribute__((ext_vector_type(8))) short bf16x8;
typedef __attribute__((ext_vector_type(4))) float f32x4;
typedef unsigned short u16;

__device__ __forceinline__ u16 f2b(float f) {   // RNE f32 -> bf16
    union { float f; unsigned u; } v; v.f = f;
    unsigned r = (v.u + 0x7fffu + ((v.u >> 16) & 1u)) >> 16;
    return (u16)r;
}

// tanh-form GELU: x * sigmoid(2y), y = 0.79788456(x + 0.044715 x^3); |err| < 3e-3
__device__ __forceinline__ float gelu_fast(float x) {
    float y = 0.7978845608f * (x + 0.044715f * x * x * x);
    float s = __expf(-2.0f * y);
    return x * __builtin_amdgcn_rcpf(1.0f + s);
}

// ---------------- receiver counts -> 1/max(count,1) ----------------
__global__ void count_kernel(const int* __restrict__ ei, float* __restrict__ cnt) {
    int e = blockIdx.x * 256 + threadIdx.x;
    if (e < NE) atomicAdd(&cnt[ei[NE + e]], 1.0f);
}

__global__ void dinv_kernel(float* __restrict__ cnt) {
    int n = blockIdx.x * 256 + threadIdx.x;
    if (n < NN) cnt[n] = 1.0f / fmaxf(cnt[n], 1.0f);
}

// ---------------- x (f32) -> hb (bf16), initial only ----------------
__global__ void h2b_kernel(const float* __restrict__ h, u16* __restrict__ hb) {
    int i = blockIdx.x * 256 + threadIdx.x;
    if (i < NN * DIM / 4) {
        float4 v = ((const float4*)h)[i];
        ushort4 o;
        o.x = f2b(v.x); o.y = f2b(v.y); o.z = f2b(v.z); o.w = f2b(v.w);
        ((ushort4*)hb)[i] = o;
    }
}

// ---------------- weights -> B-fragment-ordered bf16 ----------------
// frag[s][ks][nt][lane][j] = bf16(W[s][ks*32+(lane>>4)*8+j][nt*16+(lane&15)]), 0-padded K
__global__ void wmsg_kernel(const float* __restrict__ W, u16* __restrict__ Wf) {
    int i = blockIdx.x * 256 + threadIdx.x;
    if (i >= STEPS * NKS * NNT * 64 * 8) return;
    int j    = i & 7;
    int lane = (i >> 3) & 63;
    int nt   = (i >> 9) & 7;
    int ks   = (i >> 12) % NKS;
    int s    = (i >> 12) / NKS;
    int k = ks * 32 + (lane >> 4) * 8 + j;
    int n = nt * 16 + (lane & 15);
    float w = (k < KMSG) ? W[((size_t)s * KMSG + k) * DIM + n] : 0.0f;
    Wf[i] = f2b(w);
}

__global__ void wupd_kernel(const float* __restrict__ W, u16* __restrict__ Wf) {
    int i = blockIdx.x * 256 + threadIdx.x;
    if (i >= STEPS * NKSU * NNT * 64 * 8) return;
    int j    = i & 7;
    int lane = (i >> 3) & 63;
    int nt   = (i >> 9) & 7;
    int ks   = (i >> 12) & 7;
    int s    = i >> 15;
    int k = ks * 32 + (lane >> 4) * 8 + j;
    int n = nt * 16 + (lane & 15);
    Wf[i] = f2b(W[((size_t)s * KUPD + k) * DIM + n]);
}

// ---------------- message: bf16 MFMA GEMM + GELU + LN + atomic scatter ----------------
__global__ __launch_bounds__(256, 4)
void msg_kernel(const u16* __restrict__ hb, const float* __restrict__ pos,
                const int* __restrict__ ei, const u16* __restrict__ Wf,
                const float* __restrict__ bias, const float* __restrict__ gam,
                const float* __restrict__ bet, float* __restrict__ agg) {
    __shared__ u16 A[EPB][APITCH];
    __shared__ int rowS[EPB], colS[EPB];

    const int tid = threadIdx.x;
    const int ebase = blockIdx.x * EPB;

    if (tid < EPB) {
        int e = ebase + tid;
        int r = ei[e], c = ei[NE + e];
        rowS[tid] = r; colS[tid] = c;
        A[tid][256] = f2b(pos[r * 3 + 0] - pos[c * 3 + 0]);
        A[tid][257] = f2b(pos[r * 3 + 1] - pos[c * 3 + 1]);
        A[tid][258] = f2b(pos[r * 3 + 2] - pos[c * 3 + 2]);
        #pragma unroll
        for (int k = KMSG; k < KPAD; ++k) A[tid][k] = 0;
    }
    __syncthreads();

    for (int i = tid; i < 2048; i += 256) {
        int e = i >> 5;
        int c = i & 31;                       // 0-15: row-half, 16-31: col-half
        int node = (c < 16) ? rowS[e] : colS[e];
        int d = (c & 15) * 8;
        bf16x8 v = *(const bf16x8*)(hb + (size_t)node * DIM + d);
        *(bf16x8*)&A[e][((c < 16) ? 0 : DIM) + d] = v;
    }
    __syncthreads();

    const int wave = tid >> 6;
    const int lane = tid & 63;
    const int l15 = lane & 15;
    const int lhi = lane >> 4;

    f32x4 acc[NNT];
    #pragma unroll
    for (int t = 0; t < NNT; ++t) acc[t] = (f32x4){0.f, 0.f, 0.f, 0.f};

    const u16* Arow = &A[wave * 16 + l15][lhi * 8];

    #pragma unroll
    for (int ks = 0; ks < NKS; ++ks) {
        bf16x8 a = *(const bf16x8*)(Arow + ks * 32);
        const u16* wp = Wf + (size_t)(ks * NNT) * 512 + lane * 8;
        #pragma unroll
        for (int nt = 0; nt < NNT; ++nt) {
            bf16x8 b = *(const bf16x8*)(wp + nt * 512);
            acc[nt] = __builtin_amdgcn_mfma_f32_16x16x32_bf16(a, b, acc[nt], 0, 0, 0);
        }
    }

    float bs[NNT], gs[NNT], be[NNT];
    #pragma unroll
    for (int t = 0; t < NNT; ++t) {
        int n = t * 16 + l15;
        bs[t] = bias[n]; gs[t] = gam[n]; be[t] = bet[n];
    }

    float s0[4] = {0.f, 0.f, 0.f, 0.f}, q0[4] = {0.f, 0.f, 0.f, 0.f};
    #pragma unroll
    for (int t = 0; t < NNT; ++t)
        #pragma unroll
        for (int r = 0; r < 4; ++r) {
            float x = gelu_fast(acc[t][r] + bs[t]);
            acc[t][r] = x;
            s0[r] += x; q0[r] += x * x;
        }
    #pragma unroll
    for (int r = 0; r < 4; ++r)
        #pragma unroll
        for (int off = 1; off < 16; off <<= 1) {
            s0[r] += __shfl_xor(s0[r], off);
            q0[r] += __shfl_xor(q0[r], off);
        }

    #pragma unroll
    for (int r = 0; r < 4; ++r) {
        float mu  = s0[r] * (1.0f / 128.0f);
        float var = q0[r] * (1.0f / 128.0f) - mu * mu;
        float rs  = rsqrtf(var + LN_EPS);
        int cnode = colS[wave * 16 + lhi * 4 + r];
        float* ap = agg + (size_t)cnode * DIM + l15;
        #pragma unroll
        for (int t = 0; t < NNT; ++t) {
            float m = (acc[t][r] - mu) * rs * gs[t] + be[t];
            atomicAdd(ap + t * 16, m);
        }
    }
}

// ---------------- update: bf16 MFMA GEMM + LN + residual, writes h & hb ----------------
__global__ __launch_bounds__(256, 4)
void upd_kernel(float* __restrict__ h, u16* __restrict__ hb,
                const float* __restrict__ agg, const float* __restrict__ dinv,
                const u16* __restrict__ Wf, const float* __restrict__ bias,
                const float* __restrict__ gam, const float* __restrict__ bet) {
    __shared__ u16 Au[EPB][UPITCH];

    const int tid = threadIdx.x;
    const int nbase = blockIdx.x * EPB;

    // stage h rows (bf16 from hb): 64 nodes * 128 dims / 8 = 1024 chunks
    for (int i = tid; i < 1024; i += 256) {
        int e = i >> 4, c = i & 15, d = c * 8;
        int node = nbase + e;
        bf16x8 v = (node < NN) ? *(const bf16x8*)(hb + (size_t)node * DIM + d)
                               : (bf16x8){0,0,0,0,0,0,0,0};
        *(bf16x8*)&Au[e][d] = v;
    }
    // stage agg*dinv as bf16: 64 nodes * 128 dims / 4 = 2048 float4 chunks
    for (int i = tid; i < 2048; i += 256) {
        int e = i >> 5, c = i & 31, d = c * 4;
        int node = nbase + e;
        u16 o0 = 0, o1 = 0, o2 = 0, o3 = 0;
        if (node < NN) {
            float dv = dinv[node];
            float4 a = ((const float4*)agg)[(size_t)node * 32 + c];
            o0 = f2b(a.x * dv); o1 = f2b(a.y * dv);
            o2 = f2b(a.z * dv); o3 = f2b(a.w * dv);
        }
        ushort4 o = {o0, o1, o2, o3};
        *(ushort4*)&Au[e][DIM + d] = o;
    }
    __syncthreads();

    const int wave = tid >> 6;
    const int lane = tid & 63;
    const int l15 = lane & 15;
    const int lhi = lane >> 4;

    f32x4 acc[NNT];
    #pragma unroll
    for (int t = 0; t < NNT; ++t) acc[t] = (f32x4){0.f, 0.f, 0.f, 0.f};

    const u16* Arow = &Au[wave * 16 + l15][lhi * 8];

    #pragma unroll
    for (int ks = 0; ks < NKSU; ++ks) {
        bf16x8 a = *(const bf16x8*)(Arow + ks * 32);
        const u16* wp = Wf + (size_t)(ks * NNT) * 512 + lane * 8;
        #pragma unroll
        for (int nt = 0; nt < NNT; ++nt) {
            bf16x8 b = *(const bf16x8*)(wp + nt * 512);
            acc[nt] = __builtin_amdgcn_mfma_f32_16x16x32_bf16(a, b, acc[nt], 0, 0, 0);
        }
    }

    float bs[NNT], gs[NNT], be[NNT];
    #pragma unroll
    for (int t = 0; t < NNT; ++t) {
        int n = t * 16 + l15;
        bs[t] = bias[n]; gs[t] = gam[n]; be[t] = bet[n];
    }

    float s0[4] = {0.f, 0.f, 0.f, 0.f}, q0[4] = {0.f, 0.f, 0.f, 0.f};
    #pragma unroll
    for (int t = 0; t < NNT; ++t)
        #pragma unroll
        for (int r = 0; r < 4; ++r) {
            float x = acc[t][r] + bs[t];
            acc[t][r] = x;
            s0[r] += x; q0[r] += x * x;
        }
    #pragma unroll
    for (int r = 0; r < 4; ++r)
        #pragma unroll
        for (int off = 1; off < 16; off <<= 1) {
            s0[r] += __shfl_xor(s0[r], off);
            q0[r] += __shfl_xor(q0[r], off);
        }

    #pragma unroll
    for (int r = 0; r < 4; ++r) {
        int node = nbase + wave * 16 + lhi * 4 + r;
        if (node >= NN) continue;
        float mu  = s0[r] * (1.0f / 128.0f);
        float var = q0[r] * (1.0f / 128.0f) - mu * mu;
        float rs  = rsqrtf(var + LN_EPS);
        #pragma unroll
        for (int t = 0; t < NNT; ++t) {
            int n = t * 16 + l15;
            float u = (acc[t][r] - mu) * rs * gs[t] + be[t];
            size_t idx = (size_t)node * DIM + n;
            float out = h[idx] + u;
            h[idx] = out;
            hb[idx] = f2b(out);
        }
    }
}

// ---------------- driver ----------------
extern "C" void kernel_launch(void* const* d_in, const int* in_sizes, int n_in,
                              void* d_out, int out_size, void* d_ws, size_t ws_size,
                              hipStream_t stream) {
    const float* x      = (const float*)d_in[0];
    const float* pos    = (const float*)d_in[1];
    const int*   ei     = (const int*)d_in[2];   // delivered as int32
    const float* msg_W  = (const float*)d_in[3];
    const float* msg_b  = (const float*)d_in[4];
    const float* msg_g  = (const float*)d_in[5];
    const float* msg_be = (const float*)d_in[6];
    const float* upd_W  = (const float*)d_in[7];
    const float* upd_b  = (const float*)d_in[8];
    const float* upd_g  = (const float*)d_in[9];
    const float* upd_be = (const float*)d_in[10];

    float* h = (float*)d_out;
    char*  ws = (char*)d_ws;
    float* agg  = (float*)ws;                               // 25,600,000 B
    float* dinv = (float*)(ws + 25600000);                  //    200,000 B
    u16*   hb   = (u16*)(ws + 25800192);                    // 12,800,000 B
    u16*   Wfm  = (u16*)(ws + 38600192);                    //    294,912 B
    u16*   Wfu  = (u16*)(ws + 38895104);                    //    262,144 B

    hipMemcpyAsync(h, x, (size_t)NN * DIM * sizeof(float),
                   hipMemcpyDeviceToDevice, stream);
    h2b_kernel<<<(NN * DIM / 4 + 255) / 256, 256, 0, stream>>>(x, hb);

    hipMemsetAsync(dinv, 0, (size_t)NN * sizeof(float), stream);
    count_kernel<<<(NE + 255) / 256, 256, 0, stream>>>(ei, dinv);
    dinv_kernel<<<(NN + 255) / 256, 256, 0, stream>>>(dinv);

    wmsg_kernel<<<(STEPS * NKS * NNT * 64 * 8 + 255) / 256, 256, 0, stream>>>(msg_W, Wfm);
    wupd_kernel<<<(STEPS * NKSU * NNT * 64 * 8 + 255) / 256, 256, 0, stream>>>(upd_W, Wfu);

    for (int s = 0; s < STEPS; ++s) {
        hipMemsetAsync(agg, 0, (size_t)NN * DIM * sizeof(float), stream);
        msg_kernel<<<NE / EPB, 256, 0, stream>>>(
            hb, pos, ei, Wfm + (size_t)s * NKS * NNT * 512,
            msg_b + (size_t)s * DIM, msg_g + (size_t)s * DIM,
            msg_be + (size_t)s * DIM, agg);
        upd_kernel<<<(NN + EPB - 1) / EPB, 256, 0, stream>>>(
            h, hb, agg, dinv, Wfu + (size_t)s * NKSU * NNT * 512,
            upd_b + (size_t)s * DIM, upd_g + (size_t)s * DIM,
            upd_be + (size_t)s * DIM);
    }
}

// Round 7
// 1571.781 us; speedup vs baseline: 5.1209x; 1.0402x over previous
//
#include <hip/hip_runtime.h>
#include <math.h>

#define NN   50000
#define NE   800000
#define DIM  128
#define KMSG 259      // 2*DIM + 3
#define KUPD 256      // 2*DIM
#define STEPS 4
#define LN_EPS 1e-5f

#define EPB 64        // edges per block (NE % EPB == 0 -> 12500 blocks)
#define KPAD 288      // 9 * 32 (K padded for MFMA)
#define NKS  9        // msg K slices of 32
#define NKSU 8        // upd K slices of 32
#define NNT  8        // N tiles of 16
#define APITCH 296    // msg A pitch: 592B rows (odd*16B) -> 2-way (free) ds_read_b128
#define UPITCH 264    // upd A pitch: 528B rows -> 2-way (free)

typedef __attribute__((ext_vector_type(8))) short bf16x8;
typedef __attribute__((ext_vector_type(4))) float f32x4;
typedef unsigned short u16;

__device__ __forceinline__ u16 f2b(float f) {   // RNE f32 -> bf16
    union { float f; unsigned u; } v; v.f = f;
    unsigned r = (v.u + 0x7fffu + ((v.u >> 16) & 1u)) >> 16;
    return (u16)r;
}

// tanh-form GELU: x * sigmoid(2y), y = 0.79788456(x + 0.044715 x^3); |err| < 3e-3
__device__ __forceinline__ float gelu_fast(float x) {
    float y = 0.7978845608f * (x + 0.044715f * x * x * x);
    float s = __expf(-2.0f * y);
    return x * __builtin_amdgcn_rcpf(1.0f + s);
}

// ---------------- counting-sort by receiver + dinv ----------------
__global__ void count_kernel(const int* __restrict__ ei, int* __restrict__ cnt) {
    int e = blockIdx.x * 256 + threadIdx.x;
    if (e < NE) atomicAdd(&cnt[ei[NE + e]], 1);
}

__global__ void dinv_kernel(const int* __restrict__ cnt, float* __restrict__ dinv) {
    int n = blockIdx.x * 256 + threadIdx.x;
    if (n < NN) dinv[n] = 1.0f / fmaxf((float)cnt[n], 1.0f);
}

// single-block exclusive scan over NN counts -> cursor (CSR start offsets)
__global__ __launch_bounds__(1024)
void scan_kernel(const int* __restrict__ cnt, int* __restrict__ cursor) {
    __shared__ int part[1024];
    const int tid = threadIdx.x;
    const int CH = 49;                       // 1024*49 >= 50000
    int base = tid * CH;
    int local = 0;
    for (int i = 0; i < CH; ++i) { int n = base + i; if (n < NN) local += cnt[n]; }
    part[tid] = local;
    __syncthreads();
    for (int off = 1; off < 1024; off <<= 1) {
        int v = 0;
        if (tid >= off) v = part[tid - off];
        __syncthreads();
        if (tid >= off) part[tid] += v;
        __syncthreads();
    }
    int b = part[tid] - local;               // exclusive base of this chunk
    for (int i = 0; i < CH; ++i) {
        int n = base + i;
        if (n < NN) { cursor[n] = b; b += cnt[n]; }
    }
}

__global__ void scatter_kernel(const int* __restrict__ ei, int* __restrict__ cursor,
                               int* __restrict__ sorted) {
    int e = blockIdx.x * 256 + threadIdx.x;
    if (e < NE) {
        int c = ei[NE + e];
        int p = atomicAdd(&cursor[c], 1);
        sorted[p] = e;
    }
}

// ---------------- x (f32) -> hb (bf16), initial only ----------------
__global__ void h2b_kernel(const float* __restrict__ h, u16* __restrict__ hb) {
    int i = blockIdx.x * 256 + threadIdx.x;
    if (i < NN * DIM / 4) {
        float4 v = ((const float4*)h)[i];
        ushort4 o;
        o.x = f2b(v.x); o.y = f2b(v.y); o.z = f2b(v.z); o.w = f2b(v.w);
        ((ushort4*)hb)[i] = o;
    }
}

// ---------------- weights -> B-fragment-ordered bf16 ----------------
__global__ void wmsg_kernel(const float* __restrict__ W, u16* __restrict__ Wf) {
    int i = blockIdx.x * 256 + threadIdx.x;
    if (i >= STEPS * NKS * NNT * 64 * 8) return;
    int j    = i & 7;
    int lane = (i >> 3) & 63;
    int nt   = (i >> 9) & 7;
    int ks   = (i >> 12) % NKS;
    int s    = (i >> 12) / NKS;
    int k = ks * 32 + (lane >> 4) * 8 + j;
    int n = nt * 16 + (lane & 15);
    float w = (k < KMSG) ? W[((size_t)s * KMSG + k) * DIM + n] : 0.0f;
    Wf[i] = f2b(w);
}

__global__ void wupd_kernel(const float* __restrict__ W, u16* __restrict__ Wf) {
    int i = blockIdx.x * 256 + threadIdx.x;
    if (i >= STEPS * NKSU * NNT * 64 * 8) return;
    int j    = i & 7;
    int lane = (i >> 3) & 63;
    int nt   = (i >> 9) & 7;
    int ks   = (i >> 12) & 7;
    int s    = i >> 15;
    int k = ks * 32 + (lane >> 4) * 8 + j;
    int n = nt * 16 + (lane & 15);
    Wf[i] = f2b(W[((size_t)s * KUPD + k) * DIM + n]);
}

// ---------------- message: bf16 MFMA GEMM + GELU + LN + segmented scatter ----------------
__global__ __launch_bounds__(256, 4)
void msg_kernel(const u16* __restrict__ hb, const float* __restrict__ pos,
                const int* __restrict__ ei, const int* __restrict__ sorted,
                const u16* __restrict__ Wf,
                const float* __restrict__ bias, const float* __restrict__ gam,
                const float* __restrict__ bet, float* __restrict__ agg) {
    __shared__ u16 A[EPB][APITCH];
    __shared__ int rowS[EPB], colS[EPB];

    const int tid = threadIdx.x;
    const int ebase = blockIdx.x * EPB;

    if (tid < EPB) {
        int se = sorted[ebase + tid];        // receiver-sorted edge id
        int r = ei[se], c = ei[NE + se];
        rowS[tid] = r; colS[tid] = c;
        A[tid][256] = f2b(pos[r * 3 + 0] - pos[c * 3 + 0]);
        A[tid][257] = f2b(pos[r * 3 + 1] - pos[c * 3 + 1]);
        A[tid][258] = f2b(pos[r * 3 + 2] - pos[c * 3 + 2]);
        #pragma unroll
        for (int k = KMSG; k < KPAD; ++k) A[tid][k] = 0;
    }
    __syncthreads();

    for (int i = tid; i < 2048; i += 256) {
        int e = i >> 5;
        int c = i & 31;                       // 0-15: row-half, 16-31: col-half
        int node = (c < 16) ? rowS[e] : colS[e];
        int d = (c & 15) * 8;
        bf16x8 v = *(const bf16x8*)(hb + (size_t)node * DIM + d);
        *(bf16x8*)&A[e][((c < 16) ? 0 : DIM) + d] = v;
    }
    __syncthreads();

    const int wave = tid >> 6;
    const int lane = tid & 63;
    const int l15 = lane & 15;
    const int lhi = lane >> 4;

    f32x4 acc[NNT];
    #pragma unroll
    for (int t = 0; t < NNT; ++t) acc[t] = (f32x4){0.f, 0.f, 0.f, 0.f};

    const u16* Arow = &A[wave * 16 + l15][lhi * 8];

    #pragma unroll
    for (int ks = 0; ks < NKS; ++ks) {
        bf16x8 a = *(const bf16x8*)(Arow + ks * 32);
        const u16* wp = Wf + (size_t)(ks * NNT) * 512 + lane * 8;
        #pragma unroll
        for (int nt = 0; nt < NNT; ++nt) {
            bf16x8 b = *(const bf16x8*)(wp + nt * 512);
            acc[nt] = __builtin_amdgcn_mfma_f32_16x16x32_bf16(a, b, acc[nt], 0, 0, 0);
        }
    }

    float bs[NNT], gs[NNT], be[NNT];
    #pragma unroll
    for (int t = 0; t < NNT; ++t) {
        int n = t * 16 + l15;
        bs[t] = bias[n]; gs[t] = gam[n]; be[t] = bet[n];
    }

    // bias + GELU + LN stats (edge m = lhi*4 + r within wave's 16 edges)
    float s0[4] = {0.f, 0.f, 0.f, 0.f}, q0[4] = {0.f, 0.f, 0.f, 0.f};
    #pragma unroll
    for (int t = 0; t < NNT; ++t)
        #pragma unroll
        for (int r = 0; r < 4; ++r) {
            float x = gelu_fast(acc[t][r] + bs[t]);
            acc[t][r] = x;
            s0[r] += x; q0[r] += x * x;
        }
    #pragma unroll
    for (int r = 0; r < 4; ++r)
        #pragma unroll
        for (int off = 1; off < 16; off <<= 1) {
            s0[r] += __shfl_xor(s0[r], off);
            q0[r] += __shfl_xor(q0[r], off);
        }

    float mu[4], rsv[4];
    #pragma unroll
    for (int r = 0; r < 4; ++r) {
        mu[r] = s0[r] * (1.0f / 128.0f);
        float var = q0[r] * (1.0f / 128.0f) - mu[r] * mu[r];
        rsv[r] = rsqrtf(var + LN_EPS);
    }

    // segmented aggregation over receiver-sorted edges:
    // sum over a run: g[n]*sum((x-mu)*rs) + L*be[n]
    const int ew = wave * 16;
    if (colS[ew] == colS[ew + 15]) {
        // whole wave = one receiver: cross-lane sum, 1 coalesced atomic set per wave
        int cnode = colS[ew];
        float* ap = agg + (size_t)cnode * DIM + l15;
        #pragma unroll
        for (int t = 0; t < NNT; ++t) {
            float v = 0.f;
            #pragma unroll
            for (int r = 0; r < 4; ++r) v += (acc[t][r] - mu[r]) * rsv[r];
            v += __shfl_xor(v, 16);
            v += __shfl_xor(v, 32);
            if (lhi == 0)
                atomicAdd(ap + t * 16, gs[t] * v + 16.0f * be[t]);
        }
    } else {
        // in-lane run compression over this lane's 4 sorted edges
        int cur = colS[ew + lhi * 4];
        float rv[NNT];
        #pragma unroll
        for (int t = 0; t < NNT; ++t) rv[t] = 0.f;
        float L = 0.f;
        #pragma unroll
        for (int r = 0; r < 4; ++r) {
            int rc = colS[ew + lhi * 4 + r];
            if (rc != cur) {
                float* ap = agg + (size_t)cur * DIM + l15;
                #pragma unroll
                for (int t = 0; t < NNT; ++t) {
                    atomicAdd(ap + t * 16, gs[t] * rv[t] + L * be[t]);
                    rv[t] = 0.f;
                }
                cur = rc; L = 0.f;
            }
            #pragma unroll
            for (int t = 0; t < NNT; ++t) rv[t] += (acc[t][r] - mu[r]) * rsv[r];
            L += 1.f;
        }
        float* ap = agg + (size_t)cur * DIM + l15;
        #pragma unroll
        for (int t = 0; t < NNT; ++t)
            atomicAdd(ap + t * 16, gs[t] * rv[t] + L * be[t]);
    }
}

// ---------------- update: bf16 MFMA GEMM + LN + residual, writes h & hb ----------------
__global__ __launch_bounds__(256, 4)
void upd_kernel(float* __restrict__ h, u16* __restrict__ hb,
                const float* __restrict__ agg, const float* __restrict__ dinv,
                const u16* __restrict__ Wf, const float* __restrict__ bias,
                const float* __restrict__ gam, const float* __restrict__ bet) {
    __shared__ u16 Au[EPB][UPITCH];

    const int tid = threadIdx.x;
    const int nbase = blockIdx.x * EPB;

    for (int i = tid; i < 1024; i += 256) {
        int e = i >> 4, c = i & 15, d = c * 8;
        int node = nbase + e;
        bf16x8 v = (node < NN) ? *(const bf16x8*)(hb + (size_t)node * DIM + d)
                               : (bf16x8){0,0,0,0,0,0,0,0};
        *(bf16x8*)&Au[e][d] = v;
    }
    for (int i = tid; i < 2048; i += 256) {
        int e = i >> 5, c = i & 31, d = c * 4;
        int node = nbase + e;
        u16 o0 = 0, o1 = 0, o2 = 0, o3 = 0;
        if (node < NN) {
            float dv = dinv[node];
            float4 a = ((const float4*)agg)[(size_t)node * 32 + c];
            o0 = f2b(a.x * dv); o1 = f2b(a.y * dv);
            o2 = f2b(a.z * dv); o3 = f2b(a.w * dv);
        }
        ushort4 o = {o0, o1, o2, o3};
        *(ushort4*)&Au[e][DIM + d] = o;
    }
    __syncthreads();

    const int wave = tid >> 6;
    const int lane = tid & 63;
    const int l15 = lane & 15;
    const int lhi = lane >> 4;

    f32x4 acc[NNT];
    #pragma unroll
    for (int t = 0; t < NNT; ++t) acc[t] = (f32x4){0.f, 0.f, 0.f, 0.f};

    const u16* Arow = &Au[wave * 16 + l15][lhi * 8];

    #pragma unroll
    for (int ks = 0; ks < NKSU; ++ks) {
        bf16x8 a = *(const bf16x8*)(Arow + ks * 32);
        const u16* wp = Wf + (size_t)(ks * NNT) * 512 + lane * 8;
        #pragma unroll
        for (int nt = 0; nt < NNT; ++nt) {
            bf16x8 b = *(const bf16x8*)(wp + nt * 512);
            acc[nt] = __builtin_amdgcn_mfma_f32_16x16x32_bf16(a, b, acc[nt], 0, 0, 0);
        }
    }

    float bs[NNT], gs[NNT], be[NNT];
    #pragma unroll
    for (int t = 0; t < NNT; ++t) {
        int n = t * 16 + l15;
        bs[t] = bias[n]; gs[t] = gam[n]; be[t] = bet[n];
    }

    float s0[4] = {0.f, 0.f, 0.f, 0.f}, q0[4] = {0.f, 0.f, 0.f, 0.f};
    #pragma unroll
    for (int t = 0; t < NNT; ++t)
        #pragma unroll
        for (int r = 0; r < 4; ++r) {
            float x = acc[t][r] + bs[t];
            acc[t][r] = x;
            s0[r] += x; q0[r] += x * x;
        }
    #pragma unroll
    for (int r = 0; r < 4; ++r)
        #pragma unroll
        for (int off = 1; off < 16; off <<= 1) {
            s0[r] += __shfl_xor(s0[r], off);
            q0[r] += __shfl_xor(q0[r], off);
        }

    #pragma unroll
    for (int r = 0; r < 4; ++r) {
        int node = nbase + wave * 16 + lhi * 4 + r;
        if (node >= NN) continue;
        float mu  = s0[r] * (1.0f / 128.0f);
        float var = q0[r] * (1.0f / 128.0f) - mu * mu;
        float rs  = rsqrtf(var + LN_EPS);
        #pragma unroll
        for (int t = 0; t < NNT; ++t) {
            int n = t * 16 + l15;
            float u = (acc[t][r] - mu) * rs * gs[t] + be[t];
            size_t idx = (size_t)node * DIM + n;
            float out = h[idx] + u;
            h[idx] = out;
            hb[idx] = f2b(out);
        }
    }
}

// ---------------- driver ----------------
extern "C" void kernel_launch(void* const* d_in, const int* in_sizes, int n_in,
                              void* d_out, int out_size, void* d_ws, size_t ws_size,
                              hipStream_t stream) {
    const float* x      = (const float*)d_in[0];
    const float* pos    = (const float*)d_in[1];
    const int*   ei     = (const int*)d_in[2];   // delivered as int32
    const float* msg_W  = (const float*)d_in[3];
    const float* msg_b  = (const float*)d_in[4];
    const float* msg_g  = (const float*)d_in[5];
    const float* msg_be = (const float*)d_in[6];
    const float* upd_W  = (const float*)d_in[7];
    const float* upd_b  = (const float*)d_in[8];
    const float* upd_g  = (const float*)d_in[9];
    const float* upd_be = (const float*)d_in[10];

    float* h = (float*)d_out;
    char*  ws = (char*)d_ws;
    float* agg    = (float*)ws;                             // 25,600,000 B
    float* dinv   = (float*)(ws + 25600000);                //    200,000 B
    u16*   hb     = (u16*)(ws + 25800192);                  // 12,800,000 B
    u16*   Wfm    = (u16*)(ws + 38600192);                  //    294,912 B
    u16*   Wfu    = (u16*)(ws + 38895104);                  //    262,144 B
    int*   cnt    = (int*)(ws + 39157248);                  //    200,000 B
    int*   cursor = (int*)(ws + 39357440);                  //    200,000 B
    int*   sorted = (int*)(ws + 39557632);                  //  3,200,000 B  (end ~42.8 MB)

    hipMemcpyAsync(h, x, (size_t)NN * DIM * sizeof(float),
                   hipMemcpyDeviceToDevice, stream);
    h2b_kernel<<<(NN * DIM / 4 + 255) / 256, 256, 0, stream>>>(x, hb);

    // counting sort of edges by receiver + dinv
    hipMemsetAsync(cnt, 0, (size_t)NN * sizeof(int), stream);
    count_kernel<<<(NE + 255) / 256, 256, 0, stream>>>(ei, cnt);
    scan_kernel<<<1, 1024, 0, stream>>>(cnt, cursor);
    scatter_kernel<<<(NE + 255) / 256, 256, 0, stream>>>(ei, cursor, sorted);
    dinv_kernel<<<(NN + 255) / 256, 256, 0, stream>>>(cnt, dinv);

    wmsg_kernel<<<(STEPS * NKS * NNT * 64 * 8 + 255) / 256, 256, 0, stream>>>(msg_W, Wfm);
    wupd_kernel<<<(STEPS * NKSU * NNT * 64 * 8 + 255) / 256, 256, 0, stream>>>(upd_W, Wfu);

    for (int s = 0; s < STEPS; ++s) {
        hipMemsetAsync(agg, 0, (size_t)NN * DIM * sizeof(float), stream);
        msg_kernel<<<NE / EPB, 256, 0, stream>>>(
            hb, pos, ei, sorted, Wfm + (size_t)s * NKS * NNT * 512,
            msg_b + (size_t)s * DIM, msg_g + (size_t)s * DIM,
            msg_be + (size_t)s * DIM, agg);
        upd_kernel<<<(NN + EPB - 1) / EPB, 256, 0, stream>>>(
            h, hb, agg, dinv, Wfu + (size_t)s * NKSU * NNT * 512,
            upd_b + (size_t)s * DIM, upd_g + (size_t)s * DIM,
            upd_be + (size_t)s * DIM);
    }
}

// Round 8
// 1064.826 us; speedup vs baseline: 7.5589x; 1.4761x over previous
//
#include <hip/hip_runtime.h>
#include <math.h>

#define NN   50000
#define NE   800000
#define DIM  128
#define KMSG 259      // 2*DIM + 3
#define KUPD 256      // 2*DIM
#define STEPS 4
#define LN_EPS 1e-5f

#define EPB 64
#define KPAD 288
#define NKS  9        // fallback msg K slices of 32
#define NKSU 8        // upd K slices
#define NKSP 4        // pre K slices (K=128)
#define NNT  8        // N tiles of 16 (N=128)
#define NNTP 16       // pre N tiles (N=256)
#define APITCH 296
#define UPITCH 264

#define EGRID 2048    // edge_kernel blocks
#define WPB   8       // 32-lane workers per 256-thread block

typedef __attribute__((ext_vector_type(8))) short bf16x8;
typedef __attribute__((ext_vector_type(4))) float f32x4;
typedef unsigned short u16;

__device__ __forceinline__ u16 f2b(float f) {
    union { float f; unsigned u; } v; v.f = f;
    unsigned r = (v.u + 0x7fffu + ((v.u >> 16) & 1u)) >> 16;
    return (u16)r;
}

__device__ __forceinline__ float gelu_fast(float x) {
    float y = 0.7978845608f * (x + 0.044715f * x * x * x);
    float s = __expf(-2.0f * y);
    return x * __builtin_amdgcn_rcpf(1.0f + s);
}

// ---------------- counting-sort by receiver ----------------
__global__ void count_kernel(const int* __restrict__ ei, int* __restrict__ cnt) {
    int e = blockIdx.x * 256 + threadIdx.x;
    if (e < NE) atomicAdd(&cnt[ei[NE + e]], 1);
}

__global__ void dinv_kernel(const int* __restrict__ cnt, float* __restrict__ dinv) {
    int n = blockIdx.x * 256 + threadIdx.x;
    if (n < NN) dinv[n] = 1.0f / fmaxf((float)cnt[n], 1.0f);
}

__global__ __launch_bounds__(1024)
void scan_kernel(const int* __restrict__ cnt, int* __restrict__ cursor) {
    __shared__ int part[1024];
    const int tid = threadIdx.x;
    const int CH = 49;
    int base = tid * CH;
    int local = 0;
    for (int i = 0; i < CH; ++i) { int n = base + i; if (n < NN) local += cnt[n]; }
    part[tid] = local;
    __syncthreads();
    for (int off = 1; off < 1024; off <<= 1) {
        int v = 0;
        if (tid >= off) v = part[tid - off];
        __syncthreads();
        if (tid >= off) part[tid] += v;
        __syncthreads();
    }
    int b = part[tid] - local;
    for (int i = 0; i < CH; ++i) {
        int n = base + i;
        if (n < NN) { cursor[n] = b; b += cnt[n]; }
    }
}

// writes receiver-sorted (row,col) arrays directly
__global__ void scatter_kernel(const int* __restrict__ ei, int* __restrict__ cursor,
                               int* __restrict__ rowS, int* __restrict__ colS) {
    int e = blockIdx.x * 256 + threadIdx.x;
    if (e < NE) {
        int c = ei[NE + e];
        int p = atomicAdd(&cursor[c], 1);
        rowS[p] = ei[e]; colS[p] = c;
    }
}

// ---------------- x (f32) -> hb (bf16) ----------------
__global__ void h2b_kernel(const float* __restrict__ h, u16* __restrict__ hb) {
    int i = blockIdx.x * 256 + threadIdx.x;
    if (i < NN * DIM / 4) {
        float4 v = ((const float4*)h)[i];
        ushort4 o;
        o.x = f2b(v.x); o.y = f2b(v.y); o.z = f2b(v.z); o.w = f2b(v.w);
        ((ushort4*)hb)[i] = o;
    }
}

// ---------------- weight fragment builders ----------------
// fallback msg fragments: [s][ks=9][nt=8][lane][8]
__global__ void wmsg_kernel(const float* __restrict__ W, u16* __restrict__ Wf) {
    int i = blockIdx.x * 256 + threadIdx.x;
    if (i >= STEPS * NKS * NNT * 64 * 8) return;
    int j    = i & 7;
    int lane = (i >> 3) & 63;
    int nt   = (i >> 9) & 7;
    int ks   = (i >> 12) % NKS;
    int s    = (i >> 12) / NKS;
    int k = ks * 32 + (lane >> 4) * 8 + j;
    int n = nt * 16 + (lane & 15);
    float w = (k < KMSG) ? W[((size_t)s * KMSG + k) * DIM + n] : 0.0f;
    Wf[i] = f2b(w);
}

__global__ void wupd_kernel(const float* __restrict__ W, u16* __restrict__ Wf) {
    int i = blockIdx.x * 256 + threadIdx.x;
    if (i >= STEPS * NKSU * NNT * 64 * 8) return;
    int j    = i & 7;
    int lane = (i >> 3) & 63;
    int nt   = (i >> 9) & 7;
    int ks   = (i >> 12) & 7;
    int s    = i >> 15;
    int k = ks * 32 + (lane >> 4) * 8 + j;
    int n = nt * 16 + (lane & 15);
    Wf[i] = f2b(W[((size_t)s * KUPD + k) * DIM + n]);
}

// pre fragments: B[k][n'] with k in [0,128), n' in [0,256):
// n'<128 -> W1 = msg_W rows 0..127; n'>=128 -> W2 = rows 128..255
__global__ void wpre_kernel(const float* __restrict__ W, u16* __restrict__ Wf) {
    int i = blockIdx.x * 256 + threadIdx.x;
    if (i >= STEPS * NKSP * NNTP * 64 * 8) return;
    int j    = i & 7;
    int lane = (i >> 3) & 63;
    int nt   = (i >> 9) & 15;
    int ks   = (i >> 13) & 3;
    int s    = (i >> 15) & 3;
    int k = ks * 32 + (lane >> 4) * 8 + j;          // 0..127
    int n = nt * 16 + (lane & 15);                  // 0..255
    int krow = (n < 128) ? k : 128 + k;
    int ncol = n & 127;
    Wf[i] = f2b(W[((size_t)s * KMSG + krow) * DIM + ncol]);
}

// ---------------- pre: XW = hb * [W1|W2]  (50k x 256, f32 out) ----------------
__global__ __launch_bounds__(256, 4)
void pre_kernel(const u16* __restrict__ hb, const u16* __restrict__ Wf,
                float* __restrict__ XW) {
    __shared__ u16 Au[64][136];   // 272B rows = 17*16B -> conflict-free b128

    const int tid = threadIdx.x;
    const int nbase = blockIdx.x * 64;

    for (int i = tid; i < 1024; i += 256) {
        int e = i >> 4, c = i & 15, d = c * 8;
        int node = nbase + e;
        bf16x8 v = (node < NN) ? *(const bf16x8*)(hb + (size_t)node * DIM + d)
                               : (bf16x8){0,0,0,0,0,0,0,0};
        *(bf16x8*)&Au[e][d] = v;
    }
    __syncthreads();

    const int wave = tid >> 6;
    const int lane = tid & 63;
    const int l15 = lane & 15;
    const int lhi = lane >> 4;

    f32x4 acc[NNTP];
    #pragma unroll
    for (int t = 0; t < NNTP; ++t) acc[t] = (f32x4){0.f, 0.f, 0.f, 0.f};

    const u16* Arow = &Au[wave * 16 + l15][lhi * 8];

    #pragma unroll
    for (int ks = 0; ks < NKSP; ++ks) {
        bf16x8 a = *(const bf16x8*)(Arow + ks * 32);
        const u16* wp = Wf + (size_t)(ks * NNTP) * 512 + lane * 8;
        #pragma unroll
        for (int nt = 0; nt < NNTP; ++nt) {
            bf16x8 b = *(const bf16x8*)(wp + nt * 512);
            acc[nt] = __builtin_amdgcn_mfma_f32_16x16x32_bf16(a, b, acc[nt], 0, 0, 0);
        }
    }

    #pragma unroll
    for (int r = 0; r < 4; ++r) {
        int node = nbase + wave * 16 + lhi * 4 + r;
        if (node < NN) {
            float* out = XW + (size_t)node * 256 + l15;
            #pragma unroll
            for (int t = 0; t < NNTP; ++t) out[t * 16] = acc[t][r];
        }
    }
}

// ---------------- edge: gather+add+GELU+LN+run-accumulated scatter ----------------
__global__ __launch_bounds__(256, 4)
void edge_kernel(const float* __restrict__ XW, const float* __restrict__ pos,
                 const int* __restrict__ rowS, const int* __restrict__ colS,
                 const float* __restrict__ Wstep, const float* __restrict__ bias,
                 const float* __restrict__ gam, const float* __restrict__ bet,
                 float* __restrict__ agg, int CH) {
    const int tid = threadIdx.x;
    const int sub = tid & 31;
    const int widx = (blockIdx.x * 256 + tid) >> 5;
    int e0 = widx * CH;
    if (e0 >= NE) return;
    int e1 = e0 + CH; if (e1 > NE) e1 = NE;

    float4 bi = ((const float4*)bias)[sub];
    float4 gm = ((const float4*)gam)[sub];
    float4 bt = ((const float4*)bet)[sub];
    const float* W3 = Wstep + (size_t)256 * DIM;
    float4 w3a = ((const float4*)(W3))[sub];
    float4 w3b = ((const float4*)(W3 + DIM))[sub];
    float4 w3c = ((const float4*)(W3 + 2 * DIM))[sub];

    const float4* XW4 = (const float4*)XW;

    int row = rowS[e0], col = colS[e0];
    float4 x1 = XW4[(size_t)row * 64 + sub];
    float4 x2 = XW4[(size_t)col * 64 + 32 + sub];
    float pr0 = pos[row*3+0], pr1 = pos[row*3+1], pr2 = pos[row*3+2];
    float pc0 = pos[col*3+0], pc1 = pos[col*3+1], pc2 = pos[col*3+2];

    int cur = col;
    float4 racc = {0.f, 0.f, 0.f, 0.f};

    for (int e = e0; e < e1; ++e) {
        // prefetch next edge (2-deep pipeline)
        int nrow = row, ncol = col;
        float4 nx1 = x1, nx2 = x2;
        float npr0 = pr0, npr1 = pr1, npr2 = pr2, npc0 = pc0, npc1 = pc1, npc2 = pc2;
        if (e + 1 < e1) {
            nrow = rowS[e+1]; ncol = colS[e+1];
            nx1 = XW4[(size_t)nrow * 64 + sub];
            nx2 = XW4[(size_t)ncol * 64 + 32 + sub];
            npr0 = pos[nrow*3+0]; npr1 = pos[nrow*3+1]; npr2 = pos[nrow*3+2];
            npc0 = pos[ncol*3+0]; npc1 = pos[ncol*3+1]; npc2 = pos[ncol*3+2];
        }

        float ea0 = pr0 - pc0, ea1 = pr1 - pc1, ea2 = pr2 - pc2;
        float4 m;
        m.x = x1.x + x2.x + bi.x + ea0*w3a.x + ea1*w3b.x + ea2*w3c.x;
        m.y = x1.y + x2.y + bi.y + ea0*w3a.y + ea1*w3b.y + ea2*w3c.y;
        m.z = x1.z + x2.z + bi.z + ea0*w3a.z + ea1*w3b.z + ea2*w3c.z;
        m.w = x1.w + x2.w + bi.w + ea0*w3a.w + ea1*w3b.w + ea2*w3c.w;
        m.x = gelu_fast(m.x); m.y = gelu_fast(m.y);
        m.z = gelu_fast(m.z); m.w = gelu_fast(m.w);

        float s = m.x + m.y + m.z + m.w;
        float q = m.x*m.x + m.y*m.y + m.z*m.z + m.w*m.w;
        #pragma unroll
        for (int off = 1; off < 32; off <<= 1) {
            s += __shfl_xor(s, off);
            q += __shfl_xor(q, off);
        }
        float mu  = s * (1.0f / 128.0f);
        float var = q * (1.0f / 128.0f) - mu * mu;
        float rs  = rsqrtf(var + LN_EPS);

        if (col != cur) {   // uniform within the 32-lane worker
            float* ap = agg + (size_t)cur * DIM + sub * 4;
            atomicAdd(ap + 0, racc.x); atomicAdd(ap + 1, racc.y);
            atomicAdd(ap + 2, racc.z); atomicAdd(ap + 3, racc.w);
            racc = (float4){0.f, 0.f, 0.f, 0.f};
            cur = col;
        }
        racc.x += (m.x - mu) * rs * gm.x + bt.x;
        racc.y += (m.y - mu) * rs * gm.y + bt.y;
        racc.z += (m.z - mu) * rs * gm.z + bt.z;
        racc.w += (m.w - mu) * rs * gm.w + bt.w;

        row = nrow; col = ncol; x1 = nx1; x2 = nx2;
        pr0 = npr0; pr1 = npr1; pr2 = npr2; pc0 = npc0; pc1 = npc1; pc2 = npc2;
    }
    float* ap = agg + (size_t)cur * DIM + sub * 4;
    atomicAdd(ap + 0, racc.x); atomicAdd(ap + 1, racc.y);
    atomicAdd(ap + 2, racc.z); atomicAdd(ap + 3, racc.w);
}

// ---------------- fallback message (round-7 structure, rowS/colS arrays) ----------------
__global__ __launch_bounds__(256, 4)
void msg_kernel(const u16* __restrict__ hb, const float* __restrict__ pos,
                const int* __restrict__ rowSg, const int* __restrict__ colSg,
                const u16* __restrict__ Wf,
                const float* __restrict__ bias, const float* __restrict__ gam,
                const float* __restrict__ bet, float* __restrict__ agg) {
    __shared__ u16 A[EPB][APITCH];
    __shared__ int rowS[EPB], colS[EPB];

    const int tid = threadIdx.x;
    const int ebase = blockIdx.x * EPB;

    if (tid < EPB) {
        int r = rowSg[ebase + tid], c = colSg[ebase + tid];
        rowS[tid] = r; colS[tid] = c;
        A[tid][256] = f2b(pos[r * 3 + 0] - pos[c * 3 + 0]);
        A[tid][257] = f2b(pos[r * 3 + 1] - pos[c * 3 + 1]);
        A[tid][258] = f2b(pos[r * 3 + 2] - pos[c * 3 + 2]);
        #pragma unroll
        for (int k = KMSG; k < KPAD; ++k) A[tid][k] = 0;
    }
    __syncthreads();

    for (int i = tid; i < 2048; i += 256) {
        int e = i >> 5;
        int c = i & 31;
        int node = (c < 16) ? rowS[e] : colS[e];
        int d = (c & 15) * 8;
        bf16x8 v = *(const bf16x8*)(hb + (size_t)node * DIM + d);
        *(bf16x8*)&A[e][((c < 16) ? 0 : DIM) + d] = v;
    }
    __syncthreads();

    const int wave = tid >> 6;
    const int lane = tid & 63;
    const int l15 = lane & 15;
    const int lhi = lane >> 4;

    f32x4 acc[NNT];
    #pragma unroll
    for (int t = 0; t < NNT; ++t) acc[t] = (f32x4){0.f, 0.f, 0.f, 0.f};

    const u16* Arow = &A[wave * 16 + l15][lhi * 8];

    #pragma unroll
    for (int ks = 0; ks < NKS; ++ks) {
        bf16x8 a = *(const bf16x8*)(Arow + ks * 32);
        const u16* wp = Wf + (size_t)(ks * NNT) * 512 + lane * 8;
        #pragma unroll
        for (int nt = 0; nt < NNT; ++nt) {
            bf16x8 b = *(const bf16x8*)(wp + nt * 512);
            acc[nt] = __builtin_amdgcn_mfma_f32_16x16x32_bf16(a, b, acc[nt], 0, 0, 0);
        }
    }

    float bs[NNT], gs[NNT], be[NNT];
    #pragma unroll
    for (int t = 0; t < NNT; ++t) {
        int n = t * 16 + l15;
        bs[t] = bias[n]; gs[t] = gam[n]; be[t] = bet[n];
    }

    float s0[4] = {0.f, 0.f, 0.f, 0.f}, q0[4] = {0.f, 0.f, 0.f, 0.f};
    #pragma unroll
    for (int t = 0; t < NNT; ++t)
        #pragma unroll
        for (int r = 0; r < 4; ++r) {
            float x = gelu_fast(acc[t][r] + bs[t]);
            acc[t][r] = x;
            s0[r] += x; q0[r] += x * x;
        }
    #pragma unroll
    for (int r = 0; r < 4; ++r)
        #pragma unroll
        for (int off = 1; off < 16; off <<= 1) {
            s0[r] += __shfl_xor(s0[r], off);
            q0[r] += __shfl_xor(q0[r], off);
        }

    float mu[4], rsv[4];
    #pragma unroll
    for (int r = 0; r < 4; ++r) {
        mu[r] = s0[r] * (1.0f / 128.0f);
        float var = q0[r] * (1.0f / 128.0f) - mu[r] * mu[r];
        rsv[r] = rsqrtf(var + LN_EPS);
    }

    const int ew = wave * 16;
    if (colS[ew] == colS[ew + 15]) {
        int cnode = colS[ew];
        float* ap = agg + (size_t)cnode * DIM + l15;
        #pragma unroll
        for (int t = 0; t < NNT; ++t) {
            float v = 0.f;
            #pragma unroll
            for (int r = 0; r < 4; ++r) v += (acc[t][r] - mu[r]) * rsv[r];
            v += __shfl_xor(v, 16);
            v += __shfl_xor(v, 32);
            if (lhi == 0)
                atomicAdd(ap + t * 16, gs[t] * v + 16.0f * be[t]);
        }
    } else {
        int cur = colS[ew + lhi * 4];
        float rv[NNT];
        #pragma unroll
        for (int t = 0; t < NNT; ++t) rv[t] = 0.f;
        float L = 0.f;
        #pragma unroll
        for (int r = 0; r < 4; ++r) {
            int rc = colS[ew + lhi * 4 + r];
            if (rc != cur) {
                float* ap = agg + (size_t)cur * DIM + l15;
                #pragma unroll
                for (int t = 0; t < NNT; ++t) {
                    atomicAdd(ap + t * 16, gs[t] * rv[t] + L * be[t]);
                    rv[t] = 0.f;
                }
                cur = rc; L = 0.f;
            }
            #pragma unroll
            for (int t = 0; t < NNT; ++t) rv[t] += (acc[t][r] - mu[r]) * rsv[r];
            L += 1.f;
        }
        float* ap = agg + (size_t)cur * DIM + l15;
        #pragma unroll
        for (int t = 0; t < NNT; ++t)
            atomicAdd(ap + t * 16, gs[t] * rv[t] + L * be[t]);
    }
}

// ---------------- update: bf16 MFMA + LN + residual, writes h & hb ----------------
__global__ __launch_bounds__(256, 4)
void upd_kernel(float* __restrict__ h, u16* __restrict__ hb,
                const float* __restrict__ agg, const float* __restrict__ dinv,
                const u16* __restrict__ Wf, const float* __restrict__ bias,
                const float* __restrict__ gam, const float* __restrict__ bet) {
    __shared__ u16 Au[EPB][UPITCH];

    const int tid = threadIdx.x;
    const int nbase = blockIdx.x * EPB;

    for (int i = tid; i < 1024; i += 256) {
        int e = i >> 4, c = i & 15, d = c * 8;
        int node = nbase + e;
        bf16x8 v = (node < NN) ? *(const bf16x8*)(hb + (size_t)node * DIM + d)
                               : (bf16x8){0,0,0,0,0,0,0,0};
        *(bf16x8*)&Au[e][d] = v;
    }
    for (int i = tid; i < 2048; i += 256) {
        int e = i >> 5, c = i & 31, d = c * 4;
        int node = nbase + e;
        u16 o0 = 0, o1 = 0, o2 = 0, o3 = 0;
        if (node < NN) {
            float dv = dinv[node];
            float4 a = ((const float4*)agg)[(size_t)node * 32 + c];
            o0 = f2b(a.x * dv); o1 = f2b(a.y * dv);
            o2 = f2b(a.z * dv); o3 = f2b(a.w * dv);
        }
        ushort4 o = {o0, o1, o2, o3};
        *(ushort4*)&Au[e][DIM + d] = o;
    }
    __syncthreads();

    const int wave = tid >> 6;
    const int lane = tid & 63;
    const int l15 = lane & 15;
    const int lhi = lane >> 4;

    f32x4 acc[NNT];
    #pragma unroll
    for (int t = 0; t < NNT; ++t) acc[t] = (f32x4){0.f, 0.f, 0.f, 0.f};

    const u16* Arow = &Au[wave * 16 + l15][lhi * 8];

    #pragma unroll
    for (int ks = 0; ks < NKSU; ++ks) {
        bf16x8 a = *(const bf16x8*)(Arow + ks * 32);
        const u16* wp = Wf + (size_t)(ks * NNT) * 512 + lane * 8;
        #pragma unroll
        for (int nt = 0; nt < NNT; ++nt) {
            bf16x8 b = *(const bf16x8*)(wp + nt * 512);
            acc[nt] = __builtin_amdgcn_mfma_f32_16x16x32_bf16(a, b, acc[nt], 0, 0, 0);
        }
    }

    float bs[NNT], gs[NNT], be[NNT];
    #pragma unroll
    for (int t = 0; t < NNT; ++t) {
        int n = t * 16 + l15;
        bs[t] = bias[n]; gs[t] = gam[n]; be[t] = bet[n];
    }

    float s0[4] = {0.f, 0.f, 0.f, 0.f}, q0[4] = {0.f, 0.f, 0.f, 0.f};
    #pragma unroll
    for (int t = 0; t < NNT; ++t)
        #pragma unroll
        for (int r = 0; r < 4; ++r) {
            float x = acc[t][r] + bs[t];
            acc[t][r] = x;
            s0[r] += x; q0[r] += x * x;
        }
    #pragma unroll
    for (int r = 0; r < 4; ++r)
        #pragma unroll
        for (int off = 1; off < 16; off <<= 1) {
            s0[r] += __shfl_xor(s0[r], off);
            q0[r] += __shfl_xor(q0[r], off);
        }

    #pragma unroll
    for (int r = 0; r < 4; ++r) {
        int node = nbase + wave * 16 + lhi * 4 + r;
        if (node >= NN) continue;
        float mu  = s0[r] * (1.0f / 128.0f);
        float var = q0[r] * (1.0f / 128.0f) - mu * mu;
        float rs  = rsqrtf(var + LN_EPS);
        #pragma unroll
        for (int t = 0; t < NNT; ++t) {
            int n = t * 16 + l15;
            float u = (acc[t][r] - mu) * rs * gs[t] + be[t];
            size_t idx = (size_t)node * DIM + n;
            float out = h[idx] + u;
            h[idx] = out;
            hb[idx] = f2b(out);
        }
    }
}

// ---------------- driver ----------------
extern "C" void kernel_launch(void* const* d_in, const int* in_sizes, int n_in,
                              void* d_out, int out_size, void* d_ws, size_t ws_size,
                              hipStream_t stream) {
    const float* x      = (const float*)d_in[0];
    const float* pos    = (const float*)d_in[1];
    const int*   ei     = (const int*)d_in[2];
    const float* msg_W  = (const float*)d_in[3];
    const float* msg_b  = (const float*)d_in[4];
    const float* msg_g  = (const float*)d_in[5];
    const float* msg_be = (const float*)d_in[6];
    const float* upd_W  = (const float*)d_in[7];
    const float* upd_b  = (const float*)d_in[8];
    const float* upd_g  = (const float*)d_in[9];
    const float* upd_be = (const float*)d_in[10];

    float* h = (float*)d_out;
    char*  ws = (char*)d_ws;
    float* agg    = (float*)ws;                   // 25,600,000
    float* dinv   = (float*)(ws + 25600000);      //    200,000
    u16*   hb     = (u16*)(ws + 25800192);        // 12,800,000
    u16*   Wfu    = (u16*)(ws + 38600192);        //    262,144
    u16*   Wfp    = (u16*)(ws + 38862336);        //    262,144
    int*   cnt    = (int*)(ws + 39124480);        //    200,000
    int*   cursor = (int*)(ws + 39324672);        //    200,000
    int*   rowS   = (int*)(ws + 39524864);        //  3,200,000
    int*   colS   = (int*)(ws + 42724864);        //  3,200,000
    // exclusive region @45,924,864: big path -> XW (51,200,000 f32); small -> Wfm (294,912)
    float* XW     = (float*)(ws + 45924864);
    u16*   Wfm    = (u16*)(ws + 45924864);

    const bool big = ws_size >= 97200000ull;

    hipMemcpyAsync(h, x, (size_t)NN * DIM * sizeof(float),
                   hipMemcpyDeviceToDevice, stream);
    h2b_kernel<<<(NN * DIM / 4 + 255) / 256, 256, 0, stream>>>(x, hb);

    hipMemsetAsync(cnt, 0, (size_t)NN * sizeof(int), stream);
    count_kernel<<<(NE + 255) / 256, 256, 0, stream>>>(ei, cnt);
    scan_kernel<<<1, 1024, 0, stream>>>(cnt, cursor);
    scatter_kernel<<<(NE + 255) / 256, 256, 0, stream>>>(ei, cursor, rowS, colS);
    dinv_kernel<<<(NN + 255) / 256, 256, 0, stream>>>(cnt, dinv);

    wupd_kernel<<<(STEPS * NKSU * NNT * 64 * 8 + 255) / 256, 256, 0, stream>>>(upd_W, Wfu);
    if (big) {
        wpre_kernel<<<(STEPS * NKSP * NNTP * 64 * 8 + 255) / 256, 256, 0, stream>>>(msg_W, Wfp);
    } else {
        wmsg_kernel<<<(STEPS * NKS * NNT * 64 * 8 + 255) / 256, 256, 0, stream>>>(msg_W, Wfm);
    }

    const int totW = EGRID * WPB;
    const int CH = (NE + totW - 1) / totW;

    for (int s = 0; s < STEPS; ++s) {
        hipMemsetAsync(agg, 0, (size_t)NN * DIM * sizeof(float), stream);
        if (big) {
            pre_kernel<<<(NN + 63) / 64, 256, 0, stream>>>(
                hb, Wfp + (size_t)s * NKSP * NNTP * 512, XW);
            edge_kernel<<<EGRID, 256, 0, stream>>>(
                XW, pos, rowS, colS, msg_W + (size_t)s * KMSG * DIM,
                msg_b + (size_t)s * DIM, msg_g + (size_t)s * DIM,
                msg_be + (size_t)s * DIM, agg, CH);
        } else {
            msg_kernel<<<NE / EPB, 256, 0, stream>>>(
                hb, pos, rowS, colS, Wfm + (size_t)s * NKS * NNT * 512,
                msg_b + (size_t)s * DIM, msg_g + (size_t)s * DIM,
                msg_be + (size_t)s * DIM, agg);
        }
        upd_kernel<<<(NN + EPB - 1) / EPB, 256, 0, stream>>>(
            h, hb, agg, dinv, Wfu + (size_t)s * NKSU * NNT * 512,
            upd_b + (size_t)s * DIM, upd_g + (size_t)s * DIM,
            upd_be + (size_t)s * DIM);
    }
}

// Round 9
// 927.079 us; speedup vs baseline: 8.6820x; 1.1486x over previous
//
#include <hip/hip_runtime.h>
#include <math.h>

#define NN   50000
#define NE   800000
#define DIM  128
#define KMSG 259      // 2*DIM + 3
#define KUPD 256      // 2*DIM
#define STEPS 4
#define LN_EPS 1e-5f

#define EPB 64
#define NKSU 8        // upd K slices
#define NKSP 4        // pre K slices (K=128)
#define NNT  8        // N tiles of 16 (N=128)
#define NNTP 16       // pre N tiles (N=256)
#define UPITCH 264

typedef __attribute__((ext_vector_type(8))) short bf16x8;
typedef __attribute__((ext_vector_type(4))) float f32x4;
typedef unsigned short u16;

__device__ __forceinline__ u16 f2b(float f) {
    union { float f; unsigned u; } v; v.f = f;
    unsigned r = (v.u + 0x7fffu + ((v.u >> 16) & 1u)) >> 16;
    return (u16)r;
}

__device__ __forceinline__ float gelu_fast(float x) {
    float y = 0.7978845608f * (x + 0.044715f * x * x * x);
    float s = __expf(-2.0f * y);
    return x * __builtin_amdgcn_rcpf(1.0f + s);
}

// ---------------- counting-sort by receiver ----------------
__global__ void count_kernel(const int* __restrict__ ei, int* __restrict__ cnt) {
    int e = blockIdx.x * 256 + threadIdx.x;
    if (e < NE) atomicAdd(&cnt[ei[NE + e]], 1);
}

__global__ void dinv_kernel(const int* __restrict__ cnt, float* __restrict__ dinv) {
    int n = blockIdx.x * 256 + threadIdx.x;
    if (n < NN) dinv[n] = 1.0f / fmaxf((float)cnt[n], 1.0f);
}

// exclusive scan -> cursor (mutable) and csr0 (persistent start offsets)
__global__ __launch_bounds__(1024)
void scan_kernel(const int* __restrict__ cnt, int* __restrict__ cursor,
                 int* __restrict__ csr0) {
    __shared__ int part[1024];
    const int tid = threadIdx.x;
    const int CH = 49;
    int base = tid * CH;
    int local = 0;
    for (int i = 0; i < CH; ++i) { int n = base + i; if (n < NN) local += cnt[n]; }
    part[tid] = local;
    __syncthreads();
    for (int off = 1; off < 1024; off <<= 1) {
        int v = 0;
        if (tid >= off) v = part[tid - off];
        __syncthreads();
        if (tid >= off) part[tid] += v;
        __syncthreads();
    }
    int b = part[tid] - local;
    for (int i = 0; i < CH; ++i) {
        int n = base + i;
        if (n < NN) { cursor[n] = b; csr0[n] = b; b += cnt[n]; }
    }
}

// sorted-by-receiver sender array
__global__ void scatter_kernel(const int* __restrict__ ei, int* __restrict__ cursor,
                               int* __restrict__ rowS) {
    int e = blockIdx.x * 256 + threadIdx.x;
    if (e < NE) {
        int c = ei[NE + e];
        int p = atomicAdd(&cursor[c], 1);
        rowS[p] = ei[e];
    }
}

// ---------------- x (f32) -> hb (bf16) ----------------
__global__ void h2b_kernel(const float* __restrict__ h, u16* __restrict__ hb) {
    int i = blockIdx.x * 256 + threadIdx.x;
    if (i < NN * DIM / 4) {
        float4 v = ((const float4*)h)[i];
        ushort4 o;
        o.x = f2b(v.x); o.y = f2b(v.y); o.z = f2b(v.z); o.w = f2b(v.w);
        ((ushort4*)hb)[i] = o;
    }
}

// ---------------- weight fragment builders ----------------
__global__ void wupd_kernel(const float* __restrict__ W, u16* __restrict__ Wf) {
    int i = blockIdx.x * 256 + threadIdx.x;
    if (i >= STEPS * NKSU * NNT * 64 * 8) return;
    int j    = i & 7;
    int lane = (i >> 3) & 63;
    int nt   = (i >> 9) & 7;
    int ks   = (i >> 12) & 7;
    int s    = i >> 15;
    int k = ks * 32 + (lane >> 4) * 8 + j;
    int n = nt * 16 + (lane & 15);
    Wf[i] = f2b(W[((size_t)s * KUPD + k) * DIM + n]);
}

// pre fragments: B[k][n'], n'<128 -> W1 (rows 0..127), n'>=128 -> W2 (rows 128..255)
__global__ void wpre_kernel(const float* __restrict__ W, u16* __restrict__ Wf) {
    int i = blockIdx.x * 256 + threadIdx.x;
    if (i >= STEPS * NKSP * NNTP * 64 * 8) return;
    int j    = i & 7;
    int lane = (i >> 3) & 63;
    int nt   = (i >> 9) & 15;
    int ks   = (i >> 13) & 3;
    int s    = (i >> 15) & 3;
    int k = ks * 32 + (lane >> 4) * 8 + j;
    int n = nt * 16 + (lane & 15);
    int krow = (n < 128) ? k : 128 + k;
    int ncol = n & 127;
    Wf[i] = f2b(W[((size_t)s * KMSG + krow) * DIM + ncol]);
}

// ---------------- pre: XW = hb * [W1|W2]  (50k x 256, f32) ----------------
__global__ __launch_bounds__(256, 4)
void pre_kernel(const u16* __restrict__ hb, const u16* __restrict__ Wf,
                float* __restrict__ XW) {
    __shared__ u16 Au[64][136];

    const int tid = threadIdx.x;
    const int nbase = blockIdx.x * 64;

    for (int i = tid; i < 1024; i += 256) {
        int e = i >> 4, c = i & 15, d = c * 8;
        int node = nbase + e;
        bf16x8 v = (node < NN) ? *(const bf16x8*)(hb + (size_t)node * DIM + d)
                               : (bf16x8){0,0,0,0,0,0,0,0};
        *(bf16x8*)&Au[e][d] = v;
    }
    __syncthreads();

    const int wave = tid >> 6;
    const int lane = tid & 63;
    const int l15 = lane & 15;
    const int lhi = lane >> 4;

    f32x4 acc[NNTP];
    #pragma unroll
    for (int t = 0; t < NNTP; ++t) acc[t] = (f32x4){0.f, 0.f, 0.f, 0.f};

    const u16* Arow = &Au[wave * 16 + l15][lhi * 8];

    #pragma unroll
    for (int ks = 0; ks < NKSP; ++ks) {
        bf16x8 a = *(const bf16x8*)(Arow + ks * 32);
        const u16* wp = Wf + (size_t)(ks * NNTP) * 512 + lane * 8;
        #pragma unroll
        for (int nt = 0; nt < NNTP; ++nt) {
            bf16x8 b = *(const bf16x8*)(wp + nt * 512);
            acc[nt] = __builtin_amdgcn_mfma_f32_16x16x32_bf16(a, b, acc[nt], 0, 0, 0);
        }
    }

    #pragma unroll
    for (int r = 0; r < 4; ++r) {
        int node = nbase + wave * 16 + lhi * 4 + r;
        if (node < NN) {
            float* out = XW + (size_t)node * 256 + l15;
            #pragma unroll
            for (int t = 0; t < NNTP; ++t) out[t * 16] = acc[t][r];
        }
    }
}

// ---------------- edge: one 32-lane worker per receiver, no atomics ----------------
__global__ __launch_bounds__(256, 4)
void edge_kernel(const float* __restrict__ XW, const float* __restrict__ pos,
                 const int* __restrict__ rowS, const int* __restrict__ csr0,
                 const int* __restrict__ cnt,
                 const float* __restrict__ Wstep, const float* __restrict__ bias,
                 const float* __restrict__ gam, const float* __restrict__ bet,
                 float* __restrict__ agg) {
    const int tid = threadIdx.x;
    const int sub = tid & 31;
    const int n = (blockIdx.x * 256 + tid) >> 5;   // receiver node
    if (n >= NN) return;

    const int e0 = csr0[n];
    const int e1 = e0 + cnt[n];

    float4 bi = ((const float4*)bias)[sub];
    float4 gm = ((const float4*)gam)[sub];
    float4 bt = ((const float4*)bet)[sub];
    const float* W3 = Wstep + (size_t)256 * DIM;
    float4 w3a = ((const float4*)(W3))[sub];
    float4 w3b = ((const float4*)(W3 + DIM))[sub];
    float4 w3c = ((const float4*)(W3 + 2 * DIM))[sub];

    const float4* XW4 = (const float4*)XW;

    // receiver-side terms, loaded once
    float4 x2 = XW4[(size_t)n * 64 + 32 + sub];
    float pc0 = pos[n*3+0], pc1 = pos[n*3+1], pc2 = pos[n*3+2];
    float4 base;
    base.x = x2.x + bi.x; base.y = x2.y + bi.y;
    base.z = x2.z + bi.z; base.w = x2.w + bi.w;

    float4 racc = {0.f, 0.f, 0.f, 0.f};

    if (e0 < e1) {
        int row = rowS[e0];
        float4 x1 = XW4[(size_t)row * 64 + sub];
        float pr0 = pos[row*3+0], pr1 = pos[row*3+1], pr2 = pos[row*3+2];

        for (int e = e0; e < e1; ++e) {
            int nrow = 0; float4 nx1 = x1;
            float npr0 = 0.f, npr1 = 0.f, npr2 = 0.f;
            if (e + 1 < e1) {
                nrow = rowS[e+1];
                nx1 = XW4[(size_t)nrow * 64 + sub];
                npr0 = pos[nrow*3+0]; npr1 = pos[nrow*3+1]; npr2 = pos[nrow*3+2];
            }

            float ea0 = pr0 - pc0, ea1 = pr1 - pc1, ea2 = pr2 - pc2;
            float4 m;
            m.x = x1.x + base.x + ea0*w3a.x + ea1*w3b.x + ea2*w3c.x;
            m.y = x1.y + base.y + ea0*w3a.y + ea1*w3b.y + ea2*w3c.y;
            m.z = x1.z + base.z + ea0*w3a.z + ea1*w3b.z + ea2*w3c.z;
            m.w = x1.w + base.w + ea0*w3a.w + ea1*w3b.w + ea2*w3c.w;
            m.x = gelu_fast(m.x); m.y = gelu_fast(m.y);
            m.z = gelu_fast(m.z); m.w = gelu_fast(m.w);

            float s = m.x + m.y + m.z + m.w;
            float q = m.x*m.x + m.y*m.y + m.z*m.z + m.w*m.w;
            #pragma unroll
            for (int off = 1; off < 32; off <<= 1) {
                s += __shfl_xor(s, off);
                q += __shfl_xor(q, off);
            }
            float mu  = s * (1.0f / 128.0f);
            float var = q * (1.0f / 128.0f) - mu * mu;
            float rs  = rsqrtf(var + LN_EPS);

            racc.x += (m.x - mu) * rs * gm.x + bt.x;
            racc.y += (m.y - mu) * rs * gm.y + bt.y;
            racc.z += (m.z - mu) * rs * gm.z + bt.z;
            racc.w += (m.w - mu) * rs * gm.w + bt.w;

            row = nrow; x1 = nx1;
            pr0 = npr0; pr1 = npr1; pr2 = npr2;
        }
    }

    // plain coalesced store: this worker owns the whole agg row
    *(float4*)(agg + (size_t)n * DIM + sub * 4) = racc;
}

// ---------------- update: bf16 MFMA + LN + residual, writes h & hb ----------------
__global__ __launch_bounds__(256, 4)
void upd_kernel(float* __restrict__ h, u16* __restrict__ hb,
                const float* __restrict__ agg, const float* __restrict__ dinv,
                const u16* __restrict__ Wf, const float* __restrict__ bias,
                const float* __restrict__ gam, const float* __restrict__ bet) {
    __shared__ u16 Au[EPB][UPITCH];

    const int tid = threadIdx.x;
    const int nbase = blockIdx.x * EPB;

    for (int i = tid; i < 1024; i += 256) {
        int e = i >> 4, c = i & 15, d = c * 8;
        int node = nbase + e;
        bf16x8 v = (node < NN) ? *(const bf16x8*)(hb + (size_t)node * DIM + d)
                               : (bf16x8){0,0,0,0,0,0,0,0};
        *(bf16x8*)&Au[e][d] = v;
    }
    for (int i = tid; i < 2048; i += 256) {
        int e = i >> 5, c = i & 31, d = c * 4;
        int node = nbase + e;
        u16 o0 = 0, o1 = 0, o2 = 0, o3 = 0;
        if (node < NN) {
            float dv = dinv[node];
            float4 a = ((const float4*)agg)[(size_t)node * 32 + c];
            o0 = f2b(a.x * dv); o1 = f2b(a.y * dv);
            o2 = f2b(a.z * dv); o3 = f2b(a.w * dv);
        }
        ushort4 o = {o0, o1, o2, o3};
        *(ushort4*)&Au[e][DIM + d] = o;
    }
    __syncthreads();

    const int wave = tid >> 6;
    const int lane = tid & 63;
    const int l15 = lane & 15;
    const int lhi = lane >> 4;

    f32x4 acc[NNT];
    #pragma unroll
    for (int t = 0; t < NNT; ++t) acc[t] = (f32x4){0.f, 0.f, 0.f, 0.f};

    const u16* Arow = &Au[wave * 16 + l15][lhi * 8];

    #pragma unroll
    for (int ks = 0; ks < NKSU; ++ks) {
        bf16x8 a = *(const bf16x8*)(Arow + ks * 32);
        const u16* wp = Wf + (size_t)(ks * NNT) * 512 + lane * 8;
        #pragma unroll
        for (int nt = 0; nt < NNT; ++nt) {
            bf16x8 b = *(const bf16x8*)(wp + nt * 512);
            acc[nt] = __builtin_amdgcn_mfma_f32_16x16x32_bf16(a, b, acc[nt], 0, 0, 0);
        }
    }

    float bs[NNT], gs[NNT], be[NNT];
    #pragma unroll
    for (int t = 0; t < NNT; ++t) {
        int n = t * 16 + l15;
        bs[t] = bias[n]; gs[t] = gam[n]; be[t] = bet[n];
    }

    float s0[4] = {0.f, 0.f, 0.f, 0.f}, q0[4] = {0.f, 0.f, 0.f, 0.f};
    #pragma unroll
    for (int t = 0; t < NNT; ++t)
        #pragma unroll
        for (int r = 0; r < 4; ++r) {
            float x = acc[t][r] + bs[t];
            acc[t][r] = x;
            s0[r] += x; q0[r] += x * x;
        }
    #pragma unroll
    for (int r = 0; r < 4; ++r)
        #pragma unroll
        for (int off = 1; off < 16; off <<= 1) {
            s0[r] += __shfl_xor(s0[r], off);
            q0[r] += __shfl_xor(q0[r], off);
        }

    #pragma unroll
    for (int r = 0; r < 4; ++r) {
        int node = nbase + wave * 16 + lhi * 4 + r;
        if (node >= NN) continue;
        float mu  = s0[r] * (1.0f / 128.0f);
        float var = q0[r] * (1.0f / 128.0f) - mu * mu;
        float rs  = rsqrtf(var + LN_EPS);
        #pragma unroll
        for (int t = 0; t < NNT; ++t) {
            int n = t * 16 + l15;
            float u = (acc[t][r] - mu) * rs * gs[t] + be[t];
            size_t idx = (size_t)node * DIM + n;
            float out = h[idx] + u;
            h[idx] = out;
            hb[idx] = f2b(out);
        }
    }
}

// ---------------- driver ----------------
extern "C" void kernel_launch(void* const* d_in, const int* in_sizes, int n_in,
                              void* d_out, int out_size, void* d_ws, size_t ws_size,
                              hipStream_t stream) {
    const float* x      = (const float*)d_in[0];
    const float* pos    = (const float*)d_in[1];
    const int*   ei     = (const int*)d_in[2];
    const float* msg_W  = (const float*)d_in[3];
    const float* msg_b  = (const float*)d_in[4];
    const float* msg_g  = (const float*)d_in[5];
    const float* msg_be = (const float*)d_in[6];
    const float* upd_W  = (const float*)d_in[7];
    const float* upd_b  = (const float*)d_in[8];
    const float* upd_g  = (const float*)d_in[9];
    const float* upd_be = (const float*)d_in[10];

    float* h = (float*)d_out;
    char*  ws = (char*)d_ws;
    float* agg    = (float*)ws;                   // 25,600,000
    float* dinv   = (float*)(ws + 25600000);      //    200,000
    u16*   hb     = (u16*)(ws + 25800192);        // 12,800,000
    u16*   Wfu    = (u16*)(ws + 38600192);        //    262,144
    u16*   Wfp    = (u16*)(ws + 38862336);        //    262,144
    int*   cnt    = (int*)(ws + 39124480);        //    200,000
    int*   cursor = (int*)(ws + 39324672);        //    200,000
    int*   csr0   = (int*)(ws + 39524864);        //    200,000
    int*   rowS   = (int*)(ws + 39724864);        //  3,200,000
    float* XW     = (float*)(ws + 45924864);      // 51,200,000 (end ~97.1 MB; proven fits)

    hipMemcpyAsync(h, x, (size_t)NN * DIM * sizeof(float),
                   hipMemcpyDeviceToDevice, stream);
    h2b_kernel<<<(NN * DIM / 4 + 255) / 256, 256, 0, stream>>>(x, hb);

    hipMemsetAsync(cnt, 0, (size_t)NN * sizeof(int), stream);
    count_kernel<<<(NE + 255) / 256, 256, 0, stream>>>(ei, cnt);
    scan_kernel<<<1, 1024, 0, stream>>>(cnt, cursor, csr0);
    scatter_kernel<<<(NE + 255) / 256, 256, 0, stream>>>(ei, cursor, rowS);
    dinv_kernel<<<(NN + 255) / 256, 256, 0, stream>>>(cnt, dinv);

    wupd_kernel<<<(STEPS * NKSU * NNT * 64 * 8 + 255) / 256, 256, 0, stream>>>(upd_W, Wfu);
    wpre_kernel<<<(STEPS * NKSP * NNTP * 64 * 8 + 255) / 256, 256, 0, stream>>>(msg_W, Wfp);

    const int EBLOCKS = (NN * 32 + 255) / 256;   // 6250

    for (int s = 0; s < STEPS; ++s) {
        pre_kernel<<<(NN + 63) / 64, 256, 0, stream>>>(
            hb, Wfp + (size_t)s * NKSP * NNTP * 512, XW);
        edge_kernel<<<EBLOCKS, 256, 0, stream>>>(
            XW, pos, rowS, csr0, cnt, msg_W + (size_t)s * KMSG * DIM,
            msg_b + (size_t)s * DIM, msg_g + (size_t)s * DIM,
            msg_be + (size_t)s * DIM, agg);
        upd_kernel<<<(NN + EPB - 1) / EPB, 256, 0, stream>>>(
            h, hb, agg, dinv, Wfu + (size_t)s * NKSU * NNT * 512,
            upd_b + (size_t)s * DIM, upd_g + (size_t)s * DIM,
            upd_be + (size_t)s * DIM);
    }
}

// Round 10
// 846.445 us; speedup vs baseline: 9.5090x; 1.0953x over previous
//
#include <hip/hip_runtime.h>
#include <math.h>

#define NN   50000
#define NE   800000
#define DIM  128
#define KMSG 259      // 2*DIM + 3
#define KUPD 256      // 2*DIM
#define STEPS 4
#define LN_EPS 1e-5f

#define EPB 64
#define NKSU 8        // upd K slices
#define NKSP 4        // pre K slices (K=128)
#define NNT  8        // N tiles of 16 (N=128)
#define NNTP 16       // pre N tiles (N=256)
#define UPITCH 264
#define NBLK ((NN + 255) / 256)   // 196 scan blocks

typedef __attribute__((ext_vector_type(8))) short bf16x8;
typedef __attribute__((ext_vector_type(4))) float f32x4;
typedef unsigned short u16;

__device__ __forceinline__ u16 f2b(float f) {
    union { float f; unsigned u; } v; v.f = f;
    unsigned r = (v.u + 0x7fffu + ((v.u >> 16) & 1u)) >> 16;
    return (u16)r;
}

__device__ __forceinline__ float gelu_fast(float x) {
    float y = 0.7978845608f * (x + 0.044715f * x * x * x);
    float s = __expf(-2.0f * y);
    return x * __builtin_amdgcn_rcpf(1.0f + s);
}

// ---------------- counting-sort by receiver ----------------
__global__ void count_kernel(const int* __restrict__ ei, int* __restrict__ cnt) {
    int e = blockIdx.x * 256 + threadIdx.x;
    if (e < NE) atomicAdd(&cnt[ei[NE + e]], 1);
}

__global__ void dinv_kernel(const int* __restrict__ cnt, float* __restrict__ dinv) {
    int n = blockIdx.x * 256 + threadIdx.x;
    if (n < NN) dinv[n] = 1.0f / fmaxf((float)cnt[n], 1.0f);
}

// ---- hierarchical exclusive scan: A (block sums), B (scan sums), C (local+base) ----
__global__ void scanA_kernel(const int* __restrict__ cnt, int* __restrict__ bsum) {
    int n = blockIdx.x * 256 + threadIdx.x;
    int c = (n < NN) ? cnt[n] : 0;
    #pragma unroll
    for (int off = 1; off < 64; off <<= 1) c += __shfl_xor(c, off);
    __shared__ int ws[4];
    if ((threadIdx.x & 63) == 0) ws[threadIdx.x >> 6] = c;
    __syncthreads();
    if (threadIdx.x == 0) bsum[blockIdx.x] = ws[0] + ws[1] + ws[2] + ws[3];
}

__global__ void scanB_kernel(const int* __restrict__ bsum, int* __restrict__ boff) {
    __shared__ int sh[256];
    int tid = threadIdx.x;
    int v = (tid < NBLK) ? bsum[tid] : 0;
    sh[tid] = v;
    __syncthreads();
    for (int off = 1; off < 256; off <<= 1) {
        int t = (tid >= off) ? sh[tid - off] : 0;
        __syncthreads();
        sh[tid] += t;
        __syncthreads();
    }
    if (tid < NBLK) boff[tid] = sh[tid] - v;   // exclusive
}

__global__ void scanC_kernel(const int* __restrict__ cnt, const int* __restrict__ boff,
                             int* __restrict__ cursor, int* __restrict__ csr0) {
    __shared__ int sh[256];
    int tid = threadIdx.x;
    int n = blockIdx.x * 256 + tid;
    int c = (n < NN) ? cnt[n] : 0;
    sh[tid] = c;
    __syncthreads();
    for (int off = 1; off < 256; off <<= 1) {
        int t = (tid >= off) ? sh[tid - off] : 0;
        __syncthreads();
        sh[tid] += t;
        __syncthreads();
    }
    int ex = sh[tid] - c + boff[blockIdx.x];
    if (n < NN) { cursor[n] = ex; csr0[n] = ex; }
}

// sorted-by-receiver sender array
__global__ void scatter_kernel(const int* __restrict__ ei, int* __restrict__ cursor,
                               int* __restrict__ rowS) {
    int e = blockIdx.x * 256 + threadIdx.x;
    if (e < NE) {
        int c = ei[NE + e];
        int p = atomicAdd(&cursor[c], 1);
        rowS[p] = ei[e];
    }
}

// ---------------- x (f32) -> hb (bf16) ----------------
__global__ void h2b_kernel(const float* __restrict__ h, u16* __restrict__ hb) {
    int i = blockIdx.x * 256 + threadIdx.x;
    if (i < NN * DIM / 4) {
        float4 v = ((const float4*)h)[i];
        ushort4 o;
        o.x = f2b(v.x); o.y = f2b(v.y); o.z = f2b(v.z); o.w = f2b(v.w);
        ((ushort4*)hb)[i] = o;
    }
}

// ---------------- weight fragment builders ----------------
__global__ void wupd_kernel(const float* __restrict__ W, u16* __restrict__ Wf) {
    int i = blockIdx.x * 256 + threadIdx.x;
    if (i >= STEPS * NKSU * NNT * 64 * 8) return;
    int j    = i & 7;
    int lane = (i >> 3) & 63;
    int nt   = (i >> 9) & 7;
    int ks   = (i >> 12) & 7;
    int s    = i >> 15;
    int k = ks * 32 + (lane >> 4) * 8 + j;
    int n = nt * 16 + (lane & 15);
    Wf[i] = f2b(W[((size_t)s * KUPD + k) * DIM + n]);
}

// pre fragments: B[k][n'], n'<128 -> W1 (rows 0..127), n'>=128 -> W2 (rows 128..255)
__global__ void wpre_kernel(const float* __restrict__ W, u16* __restrict__ Wf) {
    int i = blockIdx.x * 256 + threadIdx.x;
    if (i >= STEPS * NKSP * NNTP * 64 * 8) return;
    int j    = i & 7;
    int lane = (i >> 3) & 63;
    int nt   = (i >> 9) & 15;
    int ks   = (i >> 13) & 3;
    int s    = (i >> 15) & 3;
    int k = ks * 32 + (lane >> 4) * 8 + j;
    int n = nt * 16 + (lane & 15);
    int krow = (n < 128) ? k : 128 + k;
    int ncol = n & 127;
    Wf[i] = f2b(W[((size_t)s * KMSG + krow) * DIM + ncol]);
}

// ---------------- pre: XW = hb * [W1|W2]  (50k x 256, f32) ----------------
__global__ __launch_bounds__(256, 4)
void pre_kernel(const u16* __restrict__ hb, const u16* __restrict__ Wf,
                float* __restrict__ XW) {
    __shared__ u16 Au[64][136];

    const int tid = threadIdx.x;
    const int nbase = blockIdx.x * 64;

    for (int i = tid; i < 1024; i += 256) {
        int e = i >> 4, c = i & 15, d = c * 8;
        int node = nbase + e;
        bf16x8 v = (node < NN) ? *(const bf16x8*)(hb + (size_t)node * DIM + d)
                               : (bf16x8){0,0,0,0,0,0,0,0};
        *(bf16x8*)&Au[e][d] = v;
    }
    __syncthreads();

    const int wave = tid >> 6;
    const int lane = tid & 63;
    const int l15 = lane & 15;
    const int lhi = lane >> 4;

    f32x4 acc[NNTP];
    #pragma unroll
    for (int t = 0; t < NNTP; ++t) acc[t] = (f32x4){0.f, 0.f, 0.f, 0.f};

    const u16* Arow = &Au[wave * 16 + l15][lhi * 8];

    #pragma unroll
    for (int ks = 0; ks < NKSP; ++ks) {
        bf16x8 a = *(const bf16x8*)(Arow + ks * 32);
        const u16* wp = Wf + (size_t)(ks * NNTP) * 512 + lane * 8;
        #pragma unroll
        for (int nt = 0; nt < NNTP; ++nt) {
            bf16x8 b = *(const bf16x8*)(wp + nt * 512);
            acc[nt] = __builtin_amdgcn_mfma_f32_16x16x32_bf16(a, b, acc[nt], 0, 0, 0);
        }
    }

    #pragma unroll
    for (int r = 0; r < 4; ++r) {
        int node = nbase + wave * 16 + lhi * 4 + r;
        if (node < NN) {
            float* out = XW + (size_t)node * 256 + l15;
            #pragma unroll
            for (int t = 0; t < NNTP; ++t) out[t * 16] = acc[t][r];
        }
    }
}

// ---------------- edge: one 32-lane worker per receiver, no atomics ----------------
__global__ __launch_bounds__(256, 8)
void edge_kernel(const float* __restrict__ XW, const float* __restrict__ pos,
                 const int* __restrict__ rowS, const int* __restrict__ csr0,
                 const int* __restrict__ cnt,
                 const float* __restrict__ Wstep, const float* __restrict__ bias,
                 const float* __restrict__ gam, const float* __restrict__ bet,
                 float* __restrict__ agg) {
    const int tid = threadIdx.x;
    const int sub = tid & 31;
    const int n = (blockIdx.x * 256 + tid) >> 5;   // receiver node
    if (n >= NN) return;

    const int e0 = csr0[n];
    const int e1 = e0 + cnt[n];

    float4 bi = ((const float4*)bias)[sub];
    float4 gm = ((const float4*)gam)[sub];
    float4 bt = ((const float4*)bet)[sub];
    const float* W3 = Wstep + (size_t)256 * DIM;
    float4 w3a = ((const float4*)(W3))[sub];
    float4 w3b = ((const float4*)(W3 + DIM))[sub];
    float4 w3c = ((const float4*)(W3 + 2 * DIM))[sub];

    const float4* XW4 = (const float4*)XW;

    // receiver-side terms, loaded once
    float4 x2 = XW4[(size_t)n * 64 + 32 + sub];
    float pc0 = pos[n*3+0], pc1 = pos[n*3+1], pc2 = pos[n*3+2];
    float4 base;
    base.x = x2.x + bi.x; base.y = x2.y + bi.y;
    base.z = x2.z + bi.z; base.w = x2.w + bi.w;

    float4 racc = {0.f, 0.f, 0.f, 0.f};

    if (e0 < e1) {
        int row = rowS[e0];
        float4 x1 = XW4[(size_t)row * 64 + sub];
        float pr0 = pos[row*3+0], pr1 = pos[row*3+1], pr2 = pos[row*3+2];

        for (int e = e0; e < e1; ++e) {
            int nrow = 0; float4 nx1 = x1;
            float npr0 = 0.f, npr1 = 0.f, npr2 = 0.f;
            if (e + 1 < e1) {
                nrow = rowS[e+1];
                nx1 = XW4[(size_t)nrow * 64 + sub];
                npr0 = pos[nrow*3+0]; npr1 = pos[nrow*3+1]; npr2 = pos[nrow*3+2];
            }

            float ea0 = pr0 - pc0, ea1 = pr1 - pc1, ea2 = pr2 - pc2;
            float4 m;
            m.x = x1.x + base.x + ea0*w3a.x + ea1*w3b.x + ea2*w3c.x;
            m.y = x1.y + base.y + ea0*w3a.y + ea1*w3b.y + ea2*w3c.y;
            m.z = x1.z + base.z + ea0*w3a.z + ea1*w3b.z + ea2*w3c.z;
            m.w = x1.w + base.w + ea0*w3a.w + ea1*w3b.w + ea2*w3c.w;
            m.x = gelu_fast(m.x); m.y = gelu_fast(m.y);
            m.z = gelu_fast(m.z); m.w = gelu_fast(m.w);

            float s = m.x + m.y + m.z + m.w;
            float q = m.x*m.x + m.y*m.y + m.z*m.z + m.w*m.w;
            #pragma unroll
            for (int off = 1; off < 32; off <<= 1) {
                s += __shfl_xor(s, off);
                q += __shfl_xor(q, off);
            }
            float mu  = s * (1.0f / 128.0f);
            float var = q * (1.0f / 128.0f) - mu * mu;
            float rs  = rsqrtf(var + LN_EPS);

            racc.x += (m.x - mu) * rs * gm.x + bt.x;
            racc.y += (m.y - mu) * rs * gm.y + bt.y;
            racc.z += (m.z - mu) * rs * gm.z + bt.z;
            racc.w += (m.w - mu) * rs * gm.w + bt.w;

            row = nrow; x1 = nx1;
            pr0 = npr0; pr1 = npr1; pr2 = npr2;
        }
    }

    // plain coalesced store: this worker owns the whole agg row
    *(float4*)(agg + (size_t)n * DIM + sub * 4) = racc;
}

// ---------------- update: bf16 MFMA + LN + residual, writes h & hb ----------------
__global__ __launch_bounds__(256, 4)
void upd_kernel(float* __restrict__ h, u16* __restrict__ hb,
                const float* __restrict__ agg, const float* __restrict__ dinv,
                const u16* __restrict__ Wf, const float* __restrict__ bias,
                const float* __restrict__ gam, const float* __restrict__ bet) {
    __shared__ u16 Au[EPB][UPITCH];

    const int tid = threadIdx.x;
    const int nbase = blockIdx.x * EPB;

    for (int i = tid; i < 1024; i += 256) {
        int e = i >> 4, c = i & 15, d = c * 8;
        int node = nbase + e;
        bf16x8 v = (node < NN) ? *(const bf16x8*)(hb + (size_t)node * DIM + d)
                               : (bf16x8){0,0,0,0,0,0,0,0};
        *(bf16x8*)&Au[e][d] = v;
    }
    for (int i = tid; i < 2048; i += 256) {
        int e = i >> 5, c = i & 31, d = c * 4;
        int node = nbase + e;
        u16 o0 = 0, o1 = 0, o2 = 0, o3 = 0;
        if (node < NN) {
            float dv = dinv[node];
            float4 a = ((const float4*)agg)[(size_t)node * 32 + c];
            o0 = f2b(a.x * dv); o1 = f2b(a.y * dv);
            o2 = f2b(a.z * dv); o3 = f2b(a.w * dv);
        }
        ushort4 o = {o0, o1, o2, o3};
        *(ushort4*)&Au[e][DIM + d] = o;
    }
    __syncthreads();

    const int wave = tid >> 6;
    const int lane = tid & 63;
    const int l15 = lane & 15;
    const int lhi = lane >> 4;

    f32x4 acc[NNT];
    #pragma unroll
    for (int t = 0; t < NNT; ++t) acc[t] = (f32x4){0.f, 0.f, 0.f, 0.f};

    const u16* Arow = &Au[wave * 16 + l15][lhi * 8];

    #pragma unroll
    for (int ks = 0; ks < NKSU; ++ks) {
        bf16x8 a = *(const bf16x8*)(Arow + ks * 32);
        const u16* wp = Wf + (size_t)(ks * NNT) * 512 + lane * 8;
        #pragma unroll
        for (int nt = 0; nt < NNT; ++nt) {
            bf16x8 b = *(const bf16x8*)(wp + nt * 512);
            acc[nt] = __builtin_amdgcn_mfma_f32_16x16x32_bf16(a, b, acc[nt], 0, 0, 0);
        }
    }

    float bs[NNT], gs[NNT], be[NNT];
    #pragma unroll
    for (int t = 0; t < NNT; ++t) {
        int n = t * 16 + l15;
        bs[t] = bias[n]; gs[t] = gam[n]; be[t] = bet[n];
    }

    float s0[4] = {0.f, 0.f, 0.f, 0.f}, q0[4] = {0.f, 0.f, 0.f, 0.f};
    #pragma unroll
    for (int t = 0; t < NNT; ++t)
        #pragma unroll
        for (int r = 0; r < 4; ++r) {
            float x = acc[t][r] + bs[t];
            acc[t][r] = x;
            s0[r] += x; q0[r] += x * x;
        }
    #pragma unroll
    for (int r = 0; r < 4; ++r)
        #pragma unroll
        for (int off = 1; off < 16; off <<= 1) {
            s0[r] += __shfl_xor(s0[r], off);
            q0[r] += __shfl_xor(q0[r], off);
        }

    #pragma unroll
    for (int r = 0; r < 4; ++r) {
        int node = nbase + wave * 16 + lhi * 4 + r;
        if (node >= NN) continue;
        float mu  = s0[r] * (1.0f / 128.0f);
        float var = q0[r] * (1.0f / 128.0f) - mu * mu;
        float rs  = rsqrtf(var + LN_EPS);
        #pragma unroll
        for (int t = 0; t < NNT; ++t) {
            int n = t * 16 + l15;
            float u = (acc[t][r] - mu) * rs * gs[t] + be[t];
            size_t idx = (size_t)node * DIM + n;
            float out = h[idx] + u;
            h[idx] = out;
            hb[idx] = f2b(out);
        }
    }
}

// ---------------- driver ----------------
extern "C" void kernel_launch(void* const* d_in, const int* in_sizes, int n_in,
                              void* d_out, int out_size, void* d_ws, size_t ws_size,
                              hipStream_t stream) {
    const float* x      = (const float*)d_in[0];
    const float* pos    = (const float*)d_in[1];
    const int*   ei     = (const int*)d_in[2];
    const float* msg_W  = (const float*)d_in[3];
    const float* msg_b  = (const float*)d_in[4];
    const float* msg_g  = (const float*)d_in[5];
    const float* msg_be = (const float*)d_in[6];
    const float* upd_W  = (const float*)d_in[7];
    const float* upd_b  = (const float*)d_in[8];
    const float* upd_g  = (const float*)d_in[9];
    const float* upd_be = (const float*)d_in[10];

    float* h = (float*)d_out;
    char*  ws = (char*)d_ws;
    float* agg    = (float*)ws;                   // 25,600,000
    float* dinv   = (float*)(ws + 25600000);      //    200,000
    u16*   hb     = (u16*)(ws + 25800192);        // 12,800,000
    u16*   Wfu    = (u16*)(ws + 38600192);        //    262,144
    u16*   Wfp    = (u16*)(ws + 38862336);        //    262,144
    int*   cnt    = (int*)(ws + 39124480);        //    200,000
    int*   cursor = (int*)(ws + 39324672);        //    200,000
    int*   csr0   = (int*)(ws + 39524864);        //    200,000
    int*   rowS   = (int*)(ws + 39724864);        //  3,200,000
    int*   bsum   = (int*)(ws + 42924864);        //      1,024
    int*   boff   = (int*)(ws + 42925888);        //      1,024
    float* XW     = (float*)(ws + 45924864);      // 51,200,000 (end ~97.1 MB; proven fits)

    hipMemcpyAsync(h, x, (size_t)NN * DIM * sizeof(float),
                   hipMemcpyDeviceToDevice, stream);
    h2b_kernel<<<(NN * DIM / 4 + 255) / 256, 256, 0, stream>>>(x, hb);

    hipMemsetAsync(cnt, 0, (size_t)NN * sizeof(int), stream);
    count_kernel<<<(NE + 255) / 256, 256, 0, stream>>>(ei, cnt);
    scanA_kernel<<<NBLK, 256, 0, stream>>>(cnt, bsum);
    scanB_kernel<<<1, 256, 0, stream>>>(bsum, boff);
    scanC_kernel<<<NBLK, 256, 0, stream>>>(cnt, boff, cursor, csr0);
    scatter_kernel<<<(NE + 255) / 256, 256, 0, stream>>>(ei, cursor, rowS);
    dinv_kernel<<<(NN + 255) / 256, 256, 0, stream>>>(cnt, dinv);

    wupd_kernel<<<(STEPS * NKSU * NNT * 64 * 8 + 255) / 256, 256, 0, stream>>>(upd_W, Wfu);
    wpre_kernel<<<(STEPS * NKSP * NNTP * 64 * 8 + 255) / 256, 256, 0, stream>>>(msg_W, Wfp);

    const int EBLOCKS = (NN * 32 + 255) / 256;   // 6250

    for (int s = 0; s < STEPS; ++s) {
        pre_kernel<<<(NN + 63) / 64, 256, 0, stream>>>(
            hb, Wfp + (size_t)s * NKSP * NNTP * 512, XW);
        edge_kernel<<<EBLOCKS, 256, 0, stream>>>(
            XW, pos, rowS, csr0, cnt, msg_W + (size_t)s * KMSG * DIM,
            msg_b + (size_t)s * DIM, msg_g + (size_t)s * DIM,
            msg_be + (size_t)s * DIM, agg);
        upd_kernel<<<(NN + EPB - 1) / EPB, 256, 0, stream>>>(
            h, hb, agg, dinv, Wfu + (size_t)s * NKSU * NNT * 512,
            upd_b + (size_t)s * DIM, upd_g + (size_t)s * DIM,
            upd_be + (size_t)s * DIM);
    }
}

// Round 11
// 800.176 us; speedup vs baseline: 10.0589x; 1.0578x over previous
//
#include <hip/hip_runtime.h>
#include <math.h>

#define NN   50000
#define NE   800000
#define DIM  128
#define KMSG 259      // 2*DIM + 3
#define KUPD 256      // 2*DIM
#define STEPS 4
#define LN_EPS 1e-5f

#define EPB 64
#define NKSU 8        // upd K slices
#define NKSP 4        // pre K slices (K=128)
#define NNT  8        // N tiles of 16 (N=128)
#define NNTP 16       // pre N tiles (N=256)
#define UPITCH 264
#define NBLK ((NN + 255) / 256)   // 196 scan blocks

typedef __attribute__((ext_vector_type(8))) short bf16x8;
typedef __attribute__((ext_vector_type(4))) float f32x4;
typedef unsigned short u16;

__device__ __forceinline__ u16 f2b(float f) {
    union { float f; unsigned u; } v; v.f = f;
    unsigned r = (v.u + 0x7fffu + ((v.u >> 16) & 1u)) >> 16;
    return (u16)r;
}

__device__ __forceinline__ float b2f(u16 v) {
    union { unsigned u; float f; } t; t.u = ((unsigned)v) << 16; return t.f;
}

__device__ __forceinline__ float gelu_fast(float x) {
    float y = 0.7978845608f * (x + 0.044715f * x * x * x);
    float s = __expf(-2.0f * y);
    return x * __builtin_amdgcn_rcpf(1.0f + s);
}

// ---------------- counting-sort by receiver ----------------
__global__ void count_kernel(const int* __restrict__ ei, int* __restrict__ cnt) {
    int e = blockIdx.x * 256 + threadIdx.x;
    if (e < NE) atomicAdd(&cnt[ei[NE + e]], 1);
}

__global__ void dinv_kernel(const int* __restrict__ cnt, float* __restrict__ dinv) {
    int n = blockIdx.x * 256 + threadIdx.x;
    if (n < NN) dinv[n] = 1.0f / fmaxf((float)cnt[n], 1.0f);
}

// ---- hierarchical exclusive scan ----
__global__ void scanA_kernel(const int* __restrict__ cnt, int* __restrict__ bsum) {
    int n = blockIdx.x * 256 + threadIdx.x;
    int c = (n < NN) ? cnt[n] : 0;
    #pragma unroll
    for (int off = 1; off < 64; off <<= 1) c += __shfl_xor(c, off);
    __shared__ int ws[4];
    if ((threadIdx.x & 63) == 0) ws[threadIdx.x >> 6] = c;
    __syncthreads();
    if (threadIdx.x == 0) bsum[blockIdx.x] = ws[0] + ws[1] + ws[2] + ws[3];
}

__global__ void scanB_kernel(const int* __restrict__ bsum, int* __restrict__ boff) {
    __shared__ int sh[256];
    int tid = threadIdx.x;
    int v = (tid < NBLK) ? bsum[tid] : 0;
    sh[tid] = v;
    __syncthreads();
    for (int off = 1; off < 256; off <<= 1) {
        int t = (tid >= off) ? sh[tid - off] : 0;
        __syncthreads();
        sh[tid] += t;
        __syncthreads();
    }
    if (tid < NBLK) boff[tid] = sh[tid] - v;   // exclusive
}

__global__ void scanC_kernel(const int* __restrict__ cnt, const int* __restrict__ boff,
                             int* __restrict__ cursor, int* __restrict__ csr0) {
    __shared__ int sh[256];
    int tid = threadIdx.x;
    int n = blockIdx.x * 256 + tid;
    int c = (n < NN) ? cnt[n] : 0;
    sh[tid] = c;
    __syncthreads();
    for (int off = 1; off < 256; off <<= 1) {
        int t = (tid >= off) ? sh[tid - off] : 0;
        __syncthreads();
        sh[tid] += t;
        __syncthreads();
    }
    int ex = sh[tid] - c + boff[blockIdx.x];
    if (n < NN) { cursor[n] = ex; csr0[n] = ex; }
}

__global__ void scatter_kernel(const int* __restrict__ ei, int* __restrict__ cursor,
                               int* __restrict__ rowS) {
    int e = blockIdx.x * 256 + threadIdx.x;
    if (e < NE) {
        int c = ei[NE + e];
        int p = atomicAdd(&cursor[c], 1);
        rowS[p] = ei[e];
    }
}

// ---------------- x (f32) -> hb (bf16); pos -> padded float4 ----------------
__global__ void h2b_kernel(const float* __restrict__ h, u16* __restrict__ hb) {
    int i = blockIdx.x * 256 + threadIdx.x;
    if (i < NN * DIM / 4) {
        float4 v = ((const float4*)h)[i];
        ushort4 o;
        o.x = f2b(v.x); o.y = f2b(v.y); o.z = f2b(v.z); o.w = f2b(v.w);
        ((ushort4*)hb)[i] = o;
    }
}

__global__ void posw_kernel(const float* __restrict__ pos, float* __restrict__ posW) {
    int n = blockIdx.x * 256 + threadIdx.x;
    if (n < NN) {
        float4 o = {pos[n*3+0], pos[n*3+1], pos[n*3+2], 0.f};
        ((float4*)posW)[n] = o;
    }
}

// ---------------- weight fragment builders ----------------
__global__ void wupd_kernel(const float* __restrict__ W, u16* __restrict__ Wf) {
    int i = blockIdx.x * 256 + threadIdx.x;
    if (i >= STEPS * NKSU * NNT * 64 * 8) return;
    int j    = i & 7;
    int lane = (i >> 3) & 63;
    int nt   = (i >> 9) & 7;
    int ks   = (i >> 12) & 7;
    int s    = i >> 15;
    int k = ks * 32 + (lane >> 4) * 8 + j;
    int n = nt * 16 + (lane & 15);
    Wf[i] = f2b(W[((size_t)s * KUPD + k) * DIM + n]);
}

// pre fragments: B[k][n'], n'<128 -> W1 (rows 0..127), n'>=128 -> W2 (rows 128..255)
__global__ void wpre_kernel(const float* __restrict__ W, u16* __restrict__ Wf) {
    int i = blockIdx.x * 256 + threadIdx.x;
    if (i >= STEPS * NKSP * NNTP * 64 * 8) return;
    int j    = i & 7;
    int lane = (i >> 3) & 63;
    int nt   = (i >> 9) & 15;
    int ks   = (i >> 13) & 3;
    int s    = (i >> 15) & 3;
    int k = ks * 32 + (lane >> 4) * 8 + j;
    int n = nt * 16 + (lane & 15);
    int krow = (n < 128) ? k : 128 + k;
    int ncol = n & 127;
    Wf[i] = f2b(W[((size_t)s * KMSG + krow) * DIM + ncol]);
}

// ---------------- pre: XW1b (bf16, sender half) + XW2 (f32, receiver half) ----------------
__global__ __launch_bounds__(256, 4)
void pre_kernel(const u16* __restrict__ hb, const u16* __restrict__ Wf,
                u16* __restrict__ XW1b, float* __restrict__ XW2) {
    __shared__ u16 Au[64][136];

    const int tid = threadIdx.x;
    const int nbase = blockIdx.x * 64;

    for (int i = tid; i < 1024; i += 256) {
        int e = i >> 4, c = i & 15, d = c * 8;
        int node = nbase + e;
        bf16x8 v = (node < NN) ? *(const bf16x8*)(hb + (size_t)node * DIM + d)
                               : (bf16x8){0,0,0,0,0,0,0,0};
        *(bf16x8*)&Au[e][d] = v;
    }
    __syncthreads();

    const int wave = tid >> 6;
    const int lane = tid & 63;
    const int l15 = lane & 15;
    const int lhi = lane >> 4;

    f32x4 acc[NNTP];
    #pragma unroll
    for (int t = 0; t < NNTP; ++t) acc[t] = (f32x4){0.f, 0.f, 0.f, 0.f};

    const u16* Arow = &Au[wave * 16 + l15][lhi * 8];

    #pragma unroll
    for (int ks = 0; ks < NKSP; ++ks) {
        bf16x8 a = *(const bf16x8*)(Arow + ks * 32);
        const u16* wp = Wf + (size_t)(ks * NNTP) * 512 + lane * 8;
        #pragma unroll
        for (int nt = 0; nt < NNTP; ++nt) {
            bf16x8 b = *(const bf16x8*)(wp + nt * 512);
            acc[nt] = __builtin_amdgcn_mfma_f32_16x16x32_bf16(a, b, acc[nt], 0, 0, 0);
        }
    }

    #pragma unroll
    for (int r = 0; r < 4; ++r) {
        int node = nbase + wave * 16 + lhi * 4 + r;
        if (node < NN) {
            u16*   o1 = XW1b + (size_t)node * DIM + l15;
            float* o2 = XW2  + (size_t)node * DIM + l15;
            #pragma unroll
            for (int t = 0; t < 8; ++t)  o1[t * 16] = f2b(acc[t][r]);
            #pragma unroll
            for (int t = 8; t < 16; ++t) o2[(t - 8) * 16] = acc[t][r];
        }
    }
}

// ---------------- edge: one 32-lane worker per receiver, no atomics ----------------
__global__ __launch_bounds__(256, 4)
void edge_kernel(const u16* __restrict__ XW1b, const float* __restrict__ XW2,
                 const float* __restrict__ posW,
                 const int* __restrict__ rowS, const int* __restrict__ csr0,
                 const int* __restrict__ cnt,
                 const float* __restrict__ Wstep, const float* __restrict__ bias,
                 const float* __restrict__ gam, const float* __restrict__ bet,
                 float* __restrict__ agg) {
    const int tid = threadIdx.x;
    const int sub = tid & 31;
    const int n = (blockIdx.x * 256 + tid) >> 5;   // receiver node
    if (n >= NN) return;

    const int e0 = csr0[n];
    const int e1 = e0 + cnt[n];

    float4 bi = ((const float4*)bias)[sub];
    float4 gm = ((const float4*)gam)[sub];
    float4 bt = ((const float4*)bet)[sub];
    const float* W3 = Wstep + (size_t)256 * DIM;
    float4 w3a = ((const float4*)(W3))[sub];
    float4 w3b = ((const float4*)(W3 + DIM))[sub];
    float4 w3c = ((const float4*)(W3 + 2 * DIM))[sub];

    const float4*  XW24 = (const float4*)XW2;
    const ushort4* XW14 = (const ushort4*)XW1b;
    const float4*  P4   = (const float4*)posW;

    // receiver-side terms, loaded once
    float4 x2 = XW24[(size_t)n * 32 + sub];
    float4 pc = P4[n];
    float4 base;
    base.x = x2.x + bi.x; base.y = x2.y + bi.y;
    base.z = x2.z + bi.z; base.w = x2.w + bi.w;

    float4 racc = {0.f, 0.f, 0.f, 0.f};

    if (e0 < e1) {
        int row = rowS[e0];
        ushort4 x1u = XW14[(size_t)row * 32 + sub];
        float4 pr = P4[row];

        for (int e = e0; e < e1; ++e) {
            int nrow = 0; ushort4 nx1u = x1u; float4 npr = pr;
            if (e + 1 < e1) {
                nrow = rowS[e+1];
                nx1u = XW14[(size_t)nrow * 32 + sub];
                npr = P4[nrow];
            }

            float ea0 = pr.x - pc.x, ea1 = pr.y - pc.y, ea2 = pr.z - pc.z;
            float4 m;
            m.x = b2f(x1u.x) + base.x + ea0*w3a.x + ea1*w3b.x + ea2*w3c.x;
            m.y = b2f(x1u.y) + base.y + ea0*w3a.y + ea1*w3b.y + ea2*w3c.y;
            m.z = b2f(x1u.z) + base.z + ea0*w3a.z + ea1*w3b.z + ea2*w3c.z;
            m.w = b2f(x1u.w) + base.w + ea0*w3a.w + ea1*w3b.w + ea2*w3c.w;
            m.x = gelu_fast(m.x); m.y = gelu_fast(m.y);
            m.z = gelu_fast(m.z); m.w = gelu_fast(m.w);

            float s = m.x + m.y + m.z + m.w;
            float q = m.x*m.x + m.y*m.y + m.z*m.z + m.w*m.w;
            #pragma unroll
            for (int off = 1; off < 32; off <<= 1) {
                s += __shfl_xor(s, off);
                q += __shfl_xor(q, off);
            }
            float mu  = s * (1.0f / 128.0f);
            float var = q * (1.0f / 128.0f) - mu * mu;
            float rs  = rsqrtf(var + LN_EPS);

            racc.x += (m.x - mu) * rs * gm.x + bt.x;
            racc.y += (m.y - mu) * rs * gm.y + bt.y;
            racc.z += (m.z - mu) * rs * gm.z + bt.z;
            racc.w += (m.w - mu) * rs * gm.w + bt.w;

            row = nrow; x1u = nx1u; pr = npr;
        }
    }

    *(float4*)(agg + (size_t)n * DIM + sub * 4) = racc;
}

// ---------------- update: bf16 MFMA + LN + residual, writes h & hb ----------------
__global__ __launch_bounds__(256, 4)
void upd_kernel(float* __restrict__ h, u16* __restrict__ hb,
                const float* __restrict__ agg, const float* __restrict__ dinv,
                const u16* __restrict__ Wf, const float* __restrict__ bias,
                const float* __restrict__ gam, const float* __restrict__ bet) {
    __shared__ u16 Au[EPB][UPITCH];

    const int tid = threadIdx.x;
    const int nbase = blockIdx.x * EPB;

    for (int i = tid; i < 1024; i += 256) {
        int e = i >> 4, c = i & 15, d = c * 8;
        int node = nbase + e;
        bf16x8 v = (node < NN) ? *(const bf16x8*)(hb + (size_t)node * DIM + d)
                               : (bf16x8){0,0,0,0,0,0,0,0};
        *(bf16x8*)&Au[e][d] = v;
    }
    for (int i = tid; i < 2048; i += 256) {
        int e = i >> 5, c = i & 31, d = c * 4;
        int node = nbase + e;
        u16 o0 = 0, o1 = 0, o2 = 0, o3 = 0;
        if (node < NN) {
            float dv = dinv[node];
            float4 a = ((const float4*)agg)[(size_t)node * 32 + c];
            o0 = f2b(a.x * dv); o1 = f2b(a.y * dv);
            o2 = f2b(a.z * dv); o3 = f2b(a.w * dv);
        }
        ushort4 o = {o0, o1, o2, o3};
        *(ushort4*)&Au[e][DIM + d] = o;
    }
    __syncthreads();

    const int wave = tid >> 6;
    const int lane = tid & 63;
    const int l15 = lane & 15;
    const int lhi = lane >> 4;

    f32x4 acc[NNT];
    #pragma unroll
    for (int t = 0; t < NNT; ++t) acc[t] = (f32x4){0.f, 0.f, 0.f, 0.f};

    const u16* Arow = &Au[wave * 16 + l15][lhi * 8];

    #pragma unroll
    for (int ks = 0; ks < NKSU; ++ks) {
        bf16x8 a = *(const bf16x8*)(Arow + ks * 32);
        const u16* wp = Wf + (size_t)(ks * NNT) * 512 + lane * 8;
        #pragma unroll
        for (int nt = 0; nt < NNT; ++nt) {
            bf16x8 b = *(const bf16x8*)(wp + nt * 512);
            acc[nt] = __builtin_amdgcn_mfma_f32_16x16x32_bf16(a, b, acc[nt], 0, 0, 0);
        }
    }

    float bs[NNT], gs[NNT], be[NNT];
    #pragma unroll
    for (int t = 0; t < NNT; ++t) {
        int n = t * 16 + l15;
        bs[t] = bias[n]; gs[t] = gam[n]; be[t] = bet[n];
    }

    float s0[4] = {0.f, 0.f, 0.f, 0.f}, q0[4] = {0.f, 0.f, 0.f, 0.f};
    #pragma unroll
    for (int t = 0; t < NNT; ++t)
        #pragma unroll
        for (int r = 0; r < 4; ++r) {
            float x = acc[t][r] + bs[t];
            acc[t][r] = x;
            s0[r] += x; q0[r] += x * x;
        }
    #pragma unroll
    for (int r = 0; r < 4; ++r)
        #pragma unroll
        for (int off = 1; off < 16; off <<= 1) {
            s0[r] += __shfl_xor(s0[r], off);
            q0[r] += __shfl_xor(q0[r], off);
        }

    #pragma unroll
    for (int r = 0; r < 4; ++r) {
        int node = nbase + wave * 16 + lhi * 4 + r;
        if (node >= NN) continue;
        float mu  = s0[r] * (1.0f / 128.0f);
        float var = q0[r] * (1.0f / 128.0f) - mu * mu;
        float rs  = rsqrtf(var + LN_EPS);
        #pragma unroll
        for (int t = 0; t < NNT; ++t) {
            int n = t * 16 + l15;
            float u = (acc[t][r] - mu) * rs * gs[t] + be[t];
            size_t idx = (size_t)node * DIM + n;
            float out = h[idx] + u;
            h[idx] = out;
            hb[idx] = f2b(out);
        }
    }
}

// ---------------- driver ----------------
extern "C" void kernel_launch(void* const* d_in, const int* in_sizes, int n_in,
                              void* d_out, int out_size, void* d_ws, size_t ws_size,
                              hipStream_t stream) {
    const float* x      = (const float*)d_in[0];
    const float* pos    = (const float*)d_in[1];
    const int*   ei     = (const int*)d_in[2];
    const float* msg_W  = (const float*)d_in[3];
    const float* msg_b  = (const float*)d_in[4];
    const float* msg_g  = (const float*)d_in[5];
    const float* msg_be = (const float*)d_in[6];
    const float* upd_W  = (const float*)d_in[7];
    const float* upd_b  = (const float*)d_in[8];
    const float* upd_g  = (const float*)d_in[9];
    const float* upd_be = (const float*)d_in[10];

    float* h = (float*)d_out;
    char*  ws = (char*)d_ws;
    float* agg    = (float*)ws;                   // 25,600,000
    float* dinv   = (float*)(ws + 25600000);      //    200,000
    u16*   hb     = (u16*)(ws + 25800192);        // 12,800,000
    u16*   Wfu    = (u16*)(ws + 38600192);        //    262,144
    u16*   Wfp    = (u16*)(ws + 38862336);        //    262,144
    int*   cnt    = (int*)(ws + 39124480);        //    200,000
    int*   cursor = (int*)(ws + 39324672);        //    200,000
    int*   csr0   = (int*)(ws + 39524864);        //    200,000
    int*   rowS   = (int*)(ws + 39724864);        //  3,200,000
    int*   bsum   = (int*)(ws + 42924864);        //      1,024
    int*   boff   = (int*)(ws + 42925888);        //      1,024
    float* XW2    = (float*)(ws + 45924864);      // 25,600,000
    u16*   XW1b   = (u16*)(ws + 71524864);        // 12,800,000
    float* posW   = (float*)(ws + 84324864);      //    800,000  (end ~85.1 MB; fits proven 97.1)

    hipMemcpyAsync(h, x, (size_t)NN * DIM * sizeof(float),
                   hipMemcpyDeviceToDevice, stream);
    h2b_kernel<<<(NN * DIM / 4 + 255) / 256, 256, 0, stream>>>(x, hb);
    posw_kernel<<<(NN + 255) / 256, 256, 0, stream>>>(pos, posW);

    hipMemsetAsync(cnt, 0, (size_t)NN * sizeof(int), stream);
    count_kernel<<<(NE + 255) / 256, 256, 0, stream>>>(ei, cnt);
    scanA_kernel<<<NBLK, 256, 0, stream>>>(cnt, bsum);
    scanB_kernel<<<1, 256, 0, stream>>>(bsum, boff);
    scanC_kernel<<<NBLK, 256, 0, stream>>>(cnt, boff, cursor, csr0);
    scatter_kernel<<<(NE + 255) / 256, 256, 0, stream>>>(ei, cursor, rowS);
    dinv_kernel<<<(NN + 255) / 256, 256, 0, stream>>>(cnt, dinv);

    wupd_kernel<<<(STEPS * NKSU * NNT * 64 * 8 + 255) / 256, 256, 0, stream>>>(upd_W, Wfu);
    wpre_kernel<<<(STEPS * NKSP * NNTP * 64 * 8 + 255) / 256, 256, 0, stream>>>(msg_W, Wfp);

    const int EBLOCKS = (NN * 32 + 255) / 256;   // 6250

    for (int s = 0; s < STEPS; ++s) {
        pre_kernel<<<(NN + 63) / 64, 256, 0, stream>>>(
            hb, Wfp + (size_t)s * NKSP * NNTP * 512, XW1b, XW2);
        edge_kernel<<<EBLOCKS, 256, 0, stream>>>(
            XW1b, XW2, posW, rowS, csr0, cnt, msg_W + (size_t)s * KMSG * DIM,
            msg_b + (size_t)s * DIM, msg_g + (size_t)s * DIM,
            msg_be + (size_t)s * DIM, agg);
        upd_kernel<<<(NN + EPB - 1) / EPB, 256, 0, stream>>>(
            h, hb, agg, dinv, Wfu + (size_t)s * NKSU * NNT * 512,
            upd_b + (size_t)s * DIM, upd_g + (size_t)s * DIM,
            upd_be + (size_t)s * DIM);
    }
}

// Round 12
// 731.528 us; speedup vs baseline: 11.0028x; 1.0938x over previous
//
#include <hip/hip_runtime.h>
#include <math.h>

#define NN   50000
#define NE   800000
#define DIM  128
#define KMSG 259      // 2*DIM + 3
#define KUPD 256      // 2*DIM
#define STEPS 4
#define LN_EPS 1e-5f

#define EPB 64
#define NKSU 8        // upd K slices
#define NKSP 4        // pre K slices (K=128)
#define NNT  8        // N tiles of 16 (N=128)
#define NNTP 16       // pre N tiles (N=256)
#define UPITCH 264
#define NBLK ((NN + 255) / 256)   // 196 scan blocks

typedef __attribute__((ext_vector_type(8))) short bf16x8;
typedef __attribute__((ext_vector_type(4))) float f32x4;
typedef unsigned short u16;

__device__ __forceinline__ u16 f2b(float f) {
    union { float f; unsigned u; } v; v.f = f;
    unsigned r = (v.u + 0x7fffu + ((v.u >> 16) & 1u)) >> 16;
    return (u16)r;
}

__device__ __forceinline__ float b2f(u16 v) {
    union { unsigned u; float f; } t; t.u = ((unsigned)v) << 16; return t.f;
}

__device__ __forceinline__ float gelu_fast(float x) {
    float y = 0.7978845608f * (x + 0.044715f * x * x * x);
    float s = __expf(-2.0f * y);
    return x * __builtin_amdgcn_rcpf(1.0f + s);
}

// ---------------- counting-sort by receiver ----------------
__global__ void count_kernel(const int* __restrict__ ei, int* __restrict__ cnt) {
    int e = blockIdx.x * 256 + threadIdx.x;
    if (e < NE) atomicAdd(&cnt[ei[NE + e]], 1);
}

__global__ void dinv_kernel(const int* __restrict__ cnt, float* __restrict__ dinv) {
    int n = blockIdx.x * 256 + threadIdx.x;
    if (n < NN) dinv[n] = 1.0f / fmaxf((float)cnt[n], 1.0f);
}

// ---- hierarchical exclusive scan ----
__global__ void scanA_kernel(const int* __restrict__ cnt, int* __restrict__ bsum) {
    int n = blockIdx.x * 256 + threadIdx.x;
    int c = (n < NN) ? cnt[n] : 0;
    #pragma unroll
    for (int off = 1; off < 64; off <<= 1) c += __shfl_xor(c, off);
    __shared__ int ws[4];
    if ((threadIdx.x & 63) == 0) ws[threadIdx.x >> 6] = c;
    __syncthreads();
    if (threadIdx.x == 0) bsum[blockIdx.x] = ws[0] + ws[1] + ws[2] + ws[3];
}

__global__ void scanB_kernel(const int* __restrict__ bsum, int* __restrict__ boff) {
    __shared__ int sh[256];
    int tid = threadIdx.x;
    int v = (tid < NBLK) ? bsum[tid] : 0;
    sh[tid] = v;
    __syncthreads();
    for (int off = 1; off < 256; off <<= 1) {
        int t = (tid >= off) ? sh[tid - off] : 0;
        __syncthreads();
        sh[tid] += t;
        __syncthreads();
    }
    if (tid < NBLK) boff[tid] = sh[tid] - v;   // exclusive
}

__global__ void scanC_kernel(const int* __restrict__ cnt, const int* __restrict__ boff,
                             int* __restrict__ cursor, int* __restrict__ csr0) {
    __shared__ int sh[256];
    int tid = threadIdx.x;
    int n = blockIdx.x * 256 + tid;
    int c = (n < NN) ? cnt[n] : 0;
    sh[tid] = c;
    __syncthreads();
    for (int off = 1; off < 256; off <<= 1) {
        int t = (tid >= off) ? sh[tid - off] : 0;
        __syncthreads();
        sh[tid] += t;
        __syncthreads();
    }
    int ex = sh[tid] - c + boff[blockIdx.x];
    if (n < NN) { cursor[n] = ex; csr0[n] = ex; }
}

__global__ void scatter_kernel(const int* __restrict__ ei, int* __restrict__ cursor,
                               int* __restrict__ rowS) {
    int e = blockIdx.x * 256 + threadIdx.x;
    if (e < NE) {
        int c = ei[NE + e];
        int p = atomicAdd(&cursor[c], 1);
        rowS[p] = ei[e];
    }
}

// ---------------- x (f32) -> hb (bf16); pos -> padded float4 ----------------
__global__ void h2b_kernel(const float* __restrict__ h, u16* __restrict__ hb) {
    int i = blockIdx.x * 256 + threadIdx.x;
    if (i < NN * DIM / 4) {
        float4 v = ((const float4*)h)[i];
        ushort4 o;
        o.x = f2b(v.x); o.y = f2b(v.y); o.z = f2b(v.z); o.w = f2b(v.w);
        ((ushort4*)hb)[i] = o;
    }
}

__global__ void posw_kernel(const float* __restrict__ pos, float* __restrict__ posW) {
    int n = blockIdx.x * 256 + threadIdx.x;
    if (n < NN) {
        float4 o = {pos[n*3+0], pos[n*3+1], pos[n*3+2], 0.f};
        ((float4*)posW)[n] = o;
    }
}

// ---------------- weight fragment builders ----------------
__global__ void wupd_kernel(const float* __restrict__ W, u16* __restrict__ Wf) {
    int i = blockIdx.x * 256 + threadIdx.x;
    if (i >= STEPS * NKSU * NNT * 64 * 8) return;
    int j    = i & 7;
    int lane = (i >> 3) & 63;
    int nt   = (i >> 9) & 7;
    int ks   = (i >> 12) & 7;
    int s    = i >> 15;
    int k = ks * 32 + (lane >> 4) * 8 + j;
    int n = nt * 16 + (lane & 15);
    Wf[i] = f2b(W[((size_t)s * KUPD + k) * DIM + n]);
}

// pre fragments: B[k][n'], n'<128 -> W1 (rows 0..127), n'>=128 -> W2 (rows 128..255)
__global__ void wpre_kernel(const float* __restrict__ W, u16* __restrict__ Wf) {
    int i = blockIdx.x * 256 + threadIdx.x;
    if (i >= STEPS * NKSP * NNTP * 64 * 8) return;
    int j    = i & 7;
    int lane = (i >> 3) & 63;
    int nt   = (i >> 9) & 15;
    int ks   = (i >> 13) & 3;
    int s    = (i >> 15) & 3;
    int k = ks * 32 + (lane >> 4) * 8 + j;
    int n = nt * 16 + (lane & 15);
    int krow = (n < 128) ? k : 128 + k;
    int ncol = n & 127;
    Wf[i] = f2b(W[((size_t)s * KMSG + krow) * DIM + ncol]);
}

// ---------------- pre: XW1b (bf16, sender half) + XW2 (f32, receiver half) ----------------
__global__ __launch_bounds__(256, 4)
void pre_kernel(const u16* __restrict__ hb, const u16* __restrict__ Wf,
                u16* __restrict__ XW1b, float* __restrict__ XW2) {
    __shared__ u16 Au[64][136];

    const int tid = threadIdx.x;
    const int nbase = blockIdx.x * 64;

    for (int i = tid; i < 1024; i += 256) {
        int e = i >> 4, c = i & 15, d = c * 8;
        int node = nbase + e;
        bf16x8 v = (node < NN) ? *(const bf16x8*)(hb + (size_t)node * DIM + d)
                               : (bf16x8){0,0,0,0,0,0,0,0};
        *(bf16x8*)&Au[e][d] = v;
    }
    __syncthreads();

    const int wave = tid >> 6;
    const int lane = tid & 63;
    const int l15 = lane & 15;
    const int lhi = lane >> 4;

    f32x4 acc[NNTP];
    #pragma unroll
    for (int t = 0; t < NNTP; ++t) acc[t] = (f32x4){0.f, 0.f, 0.f, 0.f};

    const u16* Arow = &Au[wave * 16 + l15][lhi * 8];

    #pragma unroll
    for (int ks = 0; ks < NKSP; ++ks) {
        bf16x8 a = *(const bf16x8*)(Arow + ks * 32);
        const u16* wp = Wf + (size_t)(ks * NNTP) * 512 + lane * 8;
        #pragma unroll
        for (int nt = 0; nt < NNTP; ++nt) {
            bf16x8 b = *(const bf16x8*)(wp + nt * 512);
            acc[nt] = __builtin_amdgcn_mfma_f32_16x16x32_bf16(a, b, acc[nt], 0, 0, 0);
        }
    }

    #pragma unroll
    for (int r = 0; r < 4; ++r) {
        int node = nbase + wave * 16 + lhi * 4 + r;
        if (node < NN) {
            u16*   o1 = XW1b + (size_t)node * DIM + l15;
            float* o2 = XW2  + (size_t)node * DIM + l15;
            #pragma unroll
            for (int t = 0; t < 8; ++t)  o1[t * 16] = f2b(acc[t][r]);
            #pragma unroll
            for (int t = 8; t < 16; ++t) o2[(t - 8) * 16] = acc[t][r];
        }
    }
}

// ---------------- edge: worker-per-receiver, factorized LN, 2-edge ILP, bf16 out ----------------
__global__ __launch_bounds__(256, 4)
void edge_kernel(const u16* __restrict__ XW1b, const float* __restrict__ XW2,
                 const float* __restrict__ posW,
                 const int* __restrict__ rowS, const int* __restrict__ csr0,
                 const int* __restrict__ cnt, const float* __restrict__ dinv,
                 const float* __restrict__ Wstep, const float* __restrict__ bias,
                 const float* __restrict__ gam, const float* __restrict__ bet,
                 u16* __restrict__ aggb) {
    const int tid = threadIdx.x;
    const int sub = tid & 31;
    const int n = (blockIdx.x * 256 + tid) >> 5;   // receiver node
    if (n >= NN) return;

    u16* out = aggb + (size_t)n * DIM + sub * 4;
    const int deg = cnt[n];
    if (deg == 0) {
        ushort4 z = {0, 0, 0, 0};
        *(ushort4*)out = z;
        return;
    }
    const int e0 = csr0[n];
    const int e1 = e0 + deg;

    float4 bi = ((const float4*)bias)[sub];
    float4 gm = ((const float4*)gam)[sub];
    float4 bt = ((const float4*)bet)[sub];
    const float* W3 = Wstep + (size_t)256 * DIM;
    float4 w3a = ((const float4*)(W3))[sub];
    float4 w3b = ((const float4*)(W3 + DIM))[sub];
    float4 w3c = ((const float4*)(W3 + 2 * DIM))[sub];

    const float4*  XW24 = (const float4*)XW2;
    const ushort4* XW14 = (const ushort4*)XW1b;
    const float4*  P4   = (const float4*)posW;

    float4 x2 = XW24[(size_t)n * 32 + sub];
    float4 pc = P4[n];
    float4 base;
    base.x = x2.x + bi.x; base.y = x2.y + bi.y;
    base.z = x2.z + bi.z; base.w = x2.w + bi.w;

    float4 R1 = {0.f, 0.f, 0.f, 0.f};
    float  S  = 0.f;

    auto edge_body = [&](ushort4 x1u, float4 pr) {
        float ea0 = pr.x - pc.x, ea1 = pr.y - pc.y, ea2 = pr.z - pc.z;
        float4 m;
        m.x = b2f(x1u.x) + base.x + ea0*w3a.x + ea1*w3b.x + ea2*w3c.x;
        m.y = b2f(x1u.y) + base.y + ea0*w3a.y + ea1*w3b.y + ea2*w3c.y;
        m.z = b2f(x1u.z) + base.z + ea0*w3a.z + ea1*w3b.z + ea2*w3c.z;
        m.w = b2f(x1u.w) + base.w + ea0*w3a.w + ea1*w3b.w + ea2*w3c.w;
        m.x = gelu_fast(m.x); m.y = gelu_fast(m.y);
        m.z = gelu_fast(m.z); m.w = gelu_fast(m.w);

        float s = m.x + m.y + m.z + m.w;
        float q = m.x*m.x + m.y*m.y + m.z*m.z + m.w*m.w;
        #pragma unroll
        for (int off = 1; off < 32; off <<= 1) {
            s += __shfl_xor(s, off);
            q += __shfl_xor(q, off);
        }
        float mu  = s * (1.0f / 128.0f);
        float var = q * (1.0f / 128.0f) - mu * mu;
        float rs  = rsqrtf(var + LN_EPS);

        R1.x = fmaf(m.x, rs, R1.x);
        R1.y = fmaf(m.y, rs, R1.y);
        R1.z = fmaf(m.z, rs, R1.z);
        R1.w = fmaf(m.w, rs, R1.w);
        S = fmaf(mu, rs, S);
    };

    int e = e0;
    if (deg & 1) {                       // peel odd edge (keeps ascending order)
        int r = rowS[e];
        edge_body(XW14[(size_t)r * 32 + sub], P4[r]);
        ++e;
    }
    if (e < e1) {
        int rA = rowS[e], rB = rowS[e + 1];
        ushort4 xA = XW14[(size_t)rA * 32 + sub];
        ushort4 xB = XW14[(size_t)rB * 32 + sub];
        float4 prA = P4[rA], prB = P4[rB];
        while (e < e1) {
            ushort4 xC = xA, xD = xB;
            float4 prC = prA, prD = prB;
            if (e + 3 < e1) {            // prefetch next pair
                int rC = rowS[e + 2], rD = rowS[e + 3];
                xC = XW14[(size_t)rC * 32 + sub];
                xD = XW14[(size_t)rD * 32 + sub];
                prC = P4[rC]; prD = P4[rD];
            }
            edge_body(xA, prA);          // independent chains -> scheduler interleaves
            edge_body(xB, prB);
            e += 2;
            xA = xC; xB = xD; prA = prC; prB = prD;
        }
    }

    // out = (gm*(R1 - S))*dinv + bt   (deg*dinv == 1 for deg>=1)
    float dv = dinv[n];
    float4 o;
    o.x = fmaf(gm.x * (R1.x - S), dv, bt.x);
    o.y = fmaf(gm.y * (R1.y - S), dv, bt.y);
    o.z = fmaf(gm.z * (R1.z - S), dv, bt.z);
    o.w = fmaf(gm.w * (R1.w - S), dv, bt.w);
    ushort4 ob = {f2b(o.x), f2b(o.y), f2b(o.z), f2b(o.w)};
    *(ushort4*)out = ob;
}

// ---------------- update: bf16 MFMA + LN + residual, writes h & hb ----------------
__global__ __launch_bounds__(256, 4)
void upd_kernel(float* __restrict__ h, u16* __restrict__ hb,
                const u16* __restrict__ aggb,
                const u16* __restrict__ Wf, const float* __restrict__ bias,
                const float* __restrict__ gam, const float* __restrict__ bet) {
    __shared__ u16 Au[EPB][UPITCH];

    const int tid = threadIdx.x;
    const int nbase = blockIdx.x * EPB;

    for (int i = tid; i < 1024; i += 256) {
        int e = i >> 4, c = i & 15, d = c * 8;
        int node = nbase + e;
        bf16x8 v = (node < NN) ? *(const bf16x8*)(hb + (size_t)node * DIM + d)
                               : (bf16x8){0,0,0,0,0,0,0,0};
        *(bf16x8*)&Au[e][d] = v;
    }
    for (int i = tid; i < 1024; i += 256) {
        int e = i >> 4, c = i & 15, d = c * 8;
        int node = nbase + e;
        bf16x8 v = (node < NN) ? *(const bf16x8*)(aggb + (size_t)node * DIM + d)
                               : (bf16x8){0,0,0,0,0,0,0,0};
        *(bf16x8*)&Au[e][DIM + d] = v;
    }
    __syncthreads();

    const int wave = tid >> 6;
    const int lane = tid & 63;
    const int l15 = lane & 15;
    const int lhi = lane >> 4;

    f32x4 acc[NNT];
    #pragma unroll
    for (int t = 0; t < NNT; ++t) acc[t] = (f32x4){0.f, 0.f, 0.f, 0.f};

    const u16* Arow = &Au[wave * 16 + l15][lhi * 8];

    #pragma unroll
    for (int ks = 0; ks < NKSU; ++ks) {
        bf16x8 a = *(const bf16x8*)(Arow + ks * 32);
        const u16* wp = Wf + (size_t)(ks * NNT) * 512 + lane * 8;
        #pragma unroll
        for (int nt = 0; nt < NNT; ++nt) {
            bf16x8 b = *(const bf16x8*)(wp + nt * 512);
            acc[nt] = __builtin_amdgcn_mfma_f32_16x16x32_bf16(a, b, acc[nt], 0, 0, 0);
        }
    }

    float bs[NNT], gs[NNT], be[NNT];
    #pragma unroll
    for (int t = 0; t < NNT; ++t) {
        int n = t * 16 + l15;
        bs[t] = bias[n]; gs[t] = gam[n]; be[t] = bet[n];
    }

    float s0[4] = {0.f, 0.f, 0.f, 0.f}, q0[4] = {0.f, 0.f, 0.f, 0.f};
    #pragma unroll
    for (int t = 0; t < NNT; ++t)
        #pragma unroll
        for (int r = 0; r < 4; ++r) {
            float x = acc[t][r] + bs[t];
            acc[t][r] = x;
            s0[r] += x; q0[r] += x * x;
        }
    #pragma unroll
    for (int r = 0; r < 4; ++r)
        #pragma unroll
        for (int off = 1; off < 16; off <<= 1) {
            s0[r] += __shfl_xor(s0[r], off);
            q0[r] += __shfl_xor(q0[r], off);
        }

    #pragma unroll
    for (int r = 0; r < 4; ++r) {
        int node = nbase + wave * 16 + lhi * 4 + r;
        if (node >= NN) continue;
        float mu  = s0[r] * (1.0f / 128.0f);
        float var = q0[r] * (1.0f / 128.0f) - mu * mu;
        float rs  = rsqrtf(var + LN_EPS);
        #pragma unroll
        for (int t = 0; t < NNT; ++t) {
            int n = t * 16 + l15;
            float u = (acc[t][r] - mu) * rs * gs[t] + be[t];
            size_t idx = (size_t)node * DIM + n;
            float out = h[idx] + u;
            h[idx] = out;
            hb[idx] = f2b(out);
        }
    }
}

// ---------------- driver ----------------
extern "C" void kernel_launch(void* const* d_in, const int* in_sizes, int n_in,
                              void* d_out, int out_size, void* d_ws, size_t ws_size,
                              hipStream_t stream) {
    const float* x      = (const float*)d_in[0];
    const float* pos    = (const float*)d_in[1];
    const int*   ei     = (const int*)d_in[2];
    const float* msg_W  = (const float*)d_in[3];
    const float* msg_b  = (const float*)d_in[4];
    const float* msg_g  = (const float*)d_in[5];
    const float* msg_be = (const float*)d_in[6];
    const float* upd_W  = (const float*)d_in[7];
    const float* upd_b  = (const float*)d_in[8];
    const float* upd_g  = (const float*)d_in[9];
    const float* upd_be = (const float*)d_in[10];

    float* h = (float*)d_out;
    char*  ws = (char*)d_ws;
    u16*   aggb   = (u16*)ws;                     // 12,800,000 (bf16, dinv folded)
    float* dinv   = (float*)(ws + 25600000);      //    200,000
    u16*   hb     = (u16*)(ws + 25800192);        // 12,800,000
    u16*   Wfu    = (u16*)(ws + 38600192);        //    262,144
    u16*   Wfp    = (u16*)(ws + 38862336);        //    262,144
    int*   cnt    = (int*)(ws + 39124480);        //    200,000
    int*   cursor = (int*)(ws + 39324672);        //    200,000
    int*   csr0   = (int*)(ws + 39524864);        //    200,000
    int*   rowS   = (int*)(ws + 39724864);        //  3,200,000
    int*   bsum   = (int*)(ws + 42924864);        //      1,024
    int*   boff   = (int*)(ws + 42925888);        //      1,024
    float* XW2    = (float*)(ws + 45924864);      // 25,600,000
    u16*   XW1b   = (u16*)(ws + 71524864);        // 12,800,000
    float* posW   = (float*)(ws + 84324864);      //    800,000  (end ~85.1 MB; fits proven 97.1)

    hipMemcpyAsync(h, x, (size_t)NN * DIM * sizeof(float),
                   hipMemcpyDeviceToDevice, stream);
    h2b_kernel<<<(NN * DIM / 4 + 255) / 256, 256, 0, stream>>>(x, hb);
    posw_kernel<<<(NN + 255) / 256, 256, 0, stream>>>(pos, posW);

    hipMemsetAsync(cnt, 0, (size_t)NN * sizeof(int), stream);
    count_kernel<<<(NE + 255) / 256, 256, 0, stream>>>(ei, cnt);
    scanA_kernel<<<NBLK, 256, 0, stream>>>(cnt, bsum);
    scanB_kernel<<<1, 256, 0, stream>>>(bsum, boff);
    scanC_kernel<<<NBLK, 256, 0, stream>>>(cnt, boff, cursor, csr0);
    scatter_kernel<<<(NE + 255) / 256, 256, 0, stream>>>(ei, cursor, rowS);
    dinv_kernel<<<(NN + 255) / 256, 256, 0, stream>>>(cnt, dinv);

    wupd_kernel<<<(STEPS * NKSU * NNT * 64 * 8 + 255) / 256, 256, 0, stream>>>(upd_W, Wfu);
    wpre_kernel<<<(STEPS * NKSP * NNTP * 64 * 8 + 255) / 256, 256, 0, stream>>>(msg_W, Wfp);

    const int EBLOCKS = (NN * 32 + 255) / 256;   // 6250

    for (int s = 0; s < STEPS; ++s) {
        pre_kernel<<<(NN + 63) / 64, 256, 0, stream>>>(
            hb, Wfp + (size_t)s * NKSP * NNTP * 512, XW1b, XW2);
        edge_kernel<<<EBLOCKS, 256, 0, stream>>>(
            XW1b, XW2, posW, rowS, csr0, cnt, dinv,
            msg_W + (size_t)s * KMSG * DIM,
            msg_b + (size_t)s * DIM, msg_g + (size_t)s * DIM,
            msg_be + (size_t)s * DIM, aggb);
        upd_kernel<<<(NN + EPB - 1) / EPB, 256, 0, stream>>>(
            h, hb, aggb, Wfu + (size_t)s * NKSU * NNT * 512,
            upd_b + (size_t)s * DIM, upd_g + (size_t)s * DIM,
            upd_be + (size_t)s * DIM);
    }
}